// Round 12
// baseline (490.656 us; speedup 1.0000x reference)
//
#include <hip/hip_runtime.h>
#include <cstdint>

typedef unsigned short u16;
typedef __bf16 bf16x8 __attribute__((ext_vector_type(8)));
typedef float f32x4 __attribute__((ext_vector_type(4)));

__device__ __forceinline__ u16 f2bf(float f) {
  union { float f; uint32_t u; } x; x.f = f;
  uint32_t r = x.u + 0x7FFFu + ((x.u >> 16) & 1u);
  return (u16)(r >> 16);
}
__device__ __forceinline__ bf16x8 ld8s(const u16* p) {
  return *reinterpret_cast<const bf16x8*>(p);
}
__device__ __forceinline__ float geluf(float x) {
  return 0.5f * x * (1.f + erff(x * 0.70710678118654752f));
}
__device__ __forceinline__ uint32_t cvtpk(float a, float b) {
  uint32_t r;
  asm("v_cvt_pk_bf16_f32 %0, %1, %2" : "=v"(r) : "v"(a), "v"(b));
  return r;
}
// async global->LDS, 16B per lane; lds dest must be wave-uniform base (+lane*16)
__device__ __forceinline__ void gload16(const u16* g, u16* l) {
  __builtin_amdgcn_global_load_lds(
      (__attribute__((address_space(1))) void*)const_cast<u16*>(g),
      (__attribute__((address_space(3))) void*)l, 16, 0, 0);
}

// ---------- batched weight prep: all transposes/converts in ONE launch ----------
struct PrepJob {
  const void* src; void* dst;
  int K, N, mode, row_off, ldo, s_lo, s_hi, blk0;
};
struct PrepArgs { PrepJob j[17]; };

__global__ __launch_bounds__(256) void wprep_kernel(PrepArgs a) {
  __shared__ float tile[32][33];
  int bid = blockIdx.x;
  int t = threadIdx.x;
  const float* src = nullptr; void* dst = nullptr;
  int K = 0, N = 0, mode = 0, roff = 0, ldo = 0, slo = 0, shi = 0, bl = 0;
#pragma unroll
  for (int i = 0; i < 17; ++i) {
    int lo = a.j[i].blk0;
    int hi = (i == 16) ? 0x7fffffff : a.j[i + 1].blk0;
    if (bid >= lo && bid < hi) {
      src = (const float*)a.j[i].src; dst = a.j[i].dst;
      K = a.j[i].K; N = a.j[i].N; mode = a.j[i].mode; roff = a.j[i].row_off;
      ldo = a.j[i].ldo; slo = a.j[i].s_lo; shi = a.j[i].s_hi; bl = bid - lo;
    }
  }
  (void)K;
  if (mode <= 1) {
    int nb = N >> 5;
    int bx = bl % nb, by = bl / nb;
    int tx = t & 31, ty = t >> 5;
    int n = bx * 32 + tx, kbase = by * 32;
#pragma unroll
    for (int r = 0; r < 4; ++r)
      tile[ty + r * 8][tx] = src[(size_t)(kbase + ty + r * 8) * N + n];
    __syncthreads();
#pragma unroll
    for (int r = 0; r < 4; ++r) {
      int nl = ty + r * 8, ng = bx * 32 + nl;
      int orow;
      if (mode == 0) orow = roff + ng;
      else {
        if (ng < 4096) orow = ((ng >> 4) << 5) + (ng & 15);
        else { int t2 = ng - 4096; orow = ((t2 >> 4) << 5) + 16 + (t2 & 15); }
      }
      float v = tile[tx][nl];
      if (mode == 0 && orow >= slo && orow < shi) v *= 0.18033688011112042f;  // 0.125*log2e
      ((u16*)dst)[(size_t)orow * ldo + kbase + tx] = f2bf(v);
    }
  } else if (mode == 2) {
    int idx = bl * 1024 + t * 4;
    float4 v = *reinterpret_cast<const float4*>(src + idx);
    ushort4 o;
    o.x = f2bf(v.x); o.y = f2bf(v.y); o.z = f2bf(v.z); o.w = f2bf(v.w);
    *reinterpret_cast<ushort4*>((u16*)dst + idx) = o;
  } else if (mode == 3) {
    int row = bl;
    int tt = row % 250;
    int d0 = t * 4;
    int i0 = d0 >> 1;
    float den0 = powf(10000.f, (float)i0 / 512.f);
    float den1 = powf(10000.f, (float)(i0 + 1) / 512.f);
    float a0 = (float)tt / den0, a1 = (float)tt / den1;
    const float* hp = src + (size_t)row * 1024 + d0;
    u16* op = (u16*)dst + (size_t)row * 1024 + d0;
    op[0] = f2bf(hp[0] + sinf(a0));
    op[1] = f2bf(hp[1] + cosf(a0));
    op[2] = f2bf(hp[2] + sinf(a1));
    op[3] = f2bf(hp[3] + cosf(a1));
  } else {
    int i2 = bl * 256 + t;
    int g = i2 >> 5, s2 = i2 & 31;
    int c2 = (s2 < 16) ? (g * 16 + s2) : (4096 + g * 16 + (s2 - 16));
    ((float*)dst)[i2] = src[c2];
  }
}

// ---------- LayerNorm: f32 [rows][1024] -> bf16 ----------
__global__ __launch_bounds__(256) void ln_kernel(const float* __restrict__ x,
                                                 const float* __restrict__ g,
                                                 const float* __restrict__ b,
                                                 u16* __restrict__ out) {
  int row = blockIdx.x;
  int tid = threadIdx.x;
  int l = tid & 63, w = tid >> 6;
  const float4 v = reinterpret_cast<const float4*>(x + (size_t)row * 1024)[tid];
  float s = v.x + v.y + v.z + v.w;
#pragma unroll
  for (int d = 1; d < 64; d <<= 1) s += __shfl_xor(s, d, 64);
  __shared__ float red[8];
  if (l == 0) red[w] = s;
  __syncthreads();
  float mean = (red[0] + red[1] + red[2] + red[3]) * (1.f / 1024.f);
  float dx = v.x - mean, dy = v.y - mean, dz = v.z - mean, dw = v.w - mean;
  float vs = dx * dx + dy * dy + dz * dz + dw * dw;
#pragma unroll
  for (int d = 1; d < 64; d <<= 1) vs += __shfl_xor(vs, d, 64);
  if (l == 0) red[4 + w] = vs;
  __syncthreads();
  float var = (red[4] + red[5] + red[6] + red[7]) * (1.f / 1024.f);
  float rstd = rsqrtf(var + 1e-5f);
  const float4 g4 = reinterpret_cast<const float4*>(g)[tid];
  const float4 b4 = reinterpret_cast<const float4*>(b)[tid];
  ushort4 o;
  o.x = f2bf(dx * rstd * g4.x + b4.x);
  o.y = f2bf(dy * rstd * g4.y + b4.y);
  o.z = f2bf(dz * rstd * g4.z + b4.z);
  o.w = f2bf(dw * rstd * g4.w + b4.w);
  reinterpret_cast<ushort4*>(out + (size_t)row * 1024)[tid] = o;
}

// ---------- GEMM 128x64 pipelined (counted vmcnt, dbuf, 3 blocks/CU) ----------
// For N=1024 GEMMs: grid (N/64, M/128) = 512 blocks = 2-3 blocks/CU.
// EPI 0: bf16 out. EPI 1: f32 out = acc + bias + res.
template <int EPI>
__global__ __launch_bounds__(256) void gemm64_kernel(
    const u16* __restrict__ A, int lda, const u16* __restrict__ Bt,
    void* __restrict__ Cv, int ldc, const float* __restrict__ bias,
    const float* __restrict__ res, int M, int N, int K) {
  __shared__ __align__(16) u16 As[2][128 * 64];
  __shared__ __align__(16) u16 Bs[2][64 * 64];
  int t = threadIdx.x;
  int l = t & 63, w = t >> 6;
  int wm = w >> 1, wn = w & 1;
  int lr = l & 15, lg = l >> 4;
  int gx = gridDim.x;
  int nwg = gx * gridDim.y;
  int orig = blockIdx.y * gx + blockIdx.x;
  int qq = nwg >> 3, rr = nwg & 7;
  int xcd = orig & 7, lin = orig >> 3;
  int wg = (xcd < rr ? xcd * (qq + 1) : rr * (qq + 1) + (xcd - rr) * qq) + lin;
  int bx = wg % gx, by = wg / gx;
  int row0 = by * 128, n0 = bx * 64;

  int lrow8 = l >> 3, lchunk = l & 7;
  int csrc = (lchunk ^ lrow8) * 8;
  int keyA = lr & 7;
  f32x4 acc[4][2];
#pragma unroll
  for (int i = 0; i < 4; ++i)
#pragma unroll
    for (int j = 0; j < 2; ++j) acc[i][j] = f32x4{0.f, 0.f, 0.f, 0.f};

  auto stage = [&](int buf, int k0) {
#pragma unroll
    for (int q = 0; q < 4; ++q) {
      int rb = q * 32 + w * 8;
      gload16(&A[(size_t)(row0 + rb + lrow8) * lda + k0 + csrc], &As[buf][rb * 64]);
    }
#pragma unroll
    for (int q = 0; q < 2; ++q) {
      int rb = q * 32 + w * 8;
      gload16(&Bt[(size_t)(n0 + rb + lrow8) * K + k0 + csrc], &Bs[buf][rb * 64]);
    }
  };

  int nk = K >> 6;
  stage(0, 0);
  if (nk > 1) {
    stage(1, 64);
    asm volatile("s_waitcnt vmcnt(6)" ::: "memory");
  } else {
    asm volatile("s_waitcnt vmcnt(0)" ::: "memory");
  }
  __builtin_amdgcn_sched_barrier(0);
  __builtin_amdgcn_s_barrier();
  int cur = 0;
  for (int ti = 0; ti < nk; ++ti) {
    __builtin_amdgcn_s_setprio(1);
#pragma unroll
    for (int kk = 0; kk < 2; ++kk) {
      bf16x8 af[4], bfv[2];
#pragma unroll
      for (int mi = 0; mi < 4; ++mi)
        af[mi] = ld8s(&As[cur][(wm * 64 + mi * 16 + lr) * 64 + ((((kk << 2) + lg) ^ keyA) << 3)]);
#pragma unroll
      for (int ni = 0; ni < 2; ++ni)
        bfv[ni] = ld8s(&Bs[cur][(wn * 32 + ni * 16 + lr) * 64 + ((((kk << 2) + lg) ^ keyA) << 3)]);
#pragma unroll
      for (int mi = 0; mi < 4; ++mi)
#pragma unroll
        for (int ni = 0; ni < 2; ++ni)
          acc[mi][ni] = __builtin_amdgcn_mfma_f32_16x16x32_bf16(af[mi], bfv[ni], acc[mi][ni], 0, 0, 0);
    }
    __builtin_amdgcn_s_setprio(0);
    __builtin_amdgcn_sched_barrier(0);
    __builtin_amdgcn_s_barrier();
    if (ti + 2 < nk) {
      stage(cur, (ti + 2) << 6);
      asm volatile("s_waitcnt vmcnt(6)" ::: "memory");
    } else {
      asm volatile("s_waitcnt vmcnt(0)" ::: "memory");
    }
    __builtin_amdgcn_sched_barrier(0);
    __builtin_amdgcn_s_barrier();
    cur ^= 1;
  }

#pragma unroll
  for (int mi = 0; mi < 4; ++mi) {
    int rowb = row0 + wm * 64 + mi * 16 + lg * 4;
#pragma unroll
    for (int ni = 0; ni < 2; ++ni) {
      int gcol = n0 + wn * 32 + ni * 16 + lr;
#pragma unroll
      for (int r = 0; r < 4; ++r) {
        int grow = rowb + r;
        float v = acc[mi][ni][r];
        if (EPI == 0)
          ((u16*)Cv)[(size_t)grow * ldc + gcol] = f2bf(v);
        else
          ((float*)Cv)[(size_t)grow * ldc + gcol] =
              v + bias[gcol] + res[(size_t)grow * ldc + gcol];
      }
    }
  }
}

// ---------- GEMM 128x128 pipelined (counted vmcnt, dbuf, 2 blocks/CU) ----------
// EPI 0: bf16 out. EPI 1: f32 = acc+bias+res. EPI 2: GEGLU paired 16-col
// blocks -> bf16 a*gelu(gate), out ld = ldc.
template <int EPI, bool GUARD>
__global__ __launch_bounds__(256) void gemm_bt_kernel(
    const u16* __restrict__ A, int lda, const u16* __restrict__ Bt,
    void* __restrict__ Cv, int ldc, const float* __restrict__ bias,
    const float* __restrict__ res, int M, int N, int K) {
  __shared__ __align__(16) u16 As[2][128 * 64];
  __shared__ __align__(16) u16 Bs[2][128 * 64];
  int t = threadIdx.x;
  int l = t & 63, w = t >> 6;
  int wm = w >> 1, wn = w & 1;
  int lr = l & 15, lg = l >> 4;
  int gx = gridDim.x;
  int nwg = gx * gridDim.y;
  int orig = blockIdx.y * gx + blockIdx.x;
  int qq = nwg >> 3, rr = nwg & 7;
  int xcd = orig & 7, lin = orig >> 3;
  int wg = (xcd < rr ? xcd * (qq + 1) : rr * (qq + 1) + (xcd - rr) * qq) + lin;
  int bx = wg % gx, by = wg / gx;
  int row0 = by * 128, n0 = bx * 128;

  int lrow8 = l >> 3, lchunk = l & 7;
  int csrc = (lchunk ^ lrow8) * 8;
  int keyA = lr & 7;
  f32x4 acc[4][4];
#pragma unroll
  for (int i = 0; i < 4; ++i)
#pragma unroll
    for (int j = 0; j < 4; ++j) acc[i][j] = f32x4{0.f, 0.f, 0.f, 0.f};

  auto stage = [&](int buf, int k0) {
#pragma unroll
    for (int q = 0; q < 4; ++q) {
      int rbase = w * 32 + q * 8;
      int r = rbase + lrow8;
      int ga = row0 + r;
      if (GUARD) { if (ga > M - 1) ga = M - 1; }
      gload16(&A[(size_t)ga * lda + k0 + csrc], &As[buf][rbase * 64]);
      gload16(&Bt[(size_t)(n0 + r) * K + k0 + csrc], &Bs[buf][rbase * 64]);
    }
  };

  int nk = K >> 6;
  stage(0, 0);
  if (nk > 1) {
    stage(1, 64);
    asm volatile("s_waitcnt vmcnt(8)" ::: "memory");
  } else {
    asm volatile("s_waitcnt vmcnt(0)" ::: "memory");
  }
  __builtin_amdgcn_sched_barrier(0);
  __builtin_amdgcn_s_barrier();
  int cur = 0;
  for (int ti = 0; ti < nk; ++ti) {
    __builtin_amdgcn_s_setprio(1);
#pragma unroll
    for (int kk = 0; kk < 2; ++kk) {
      bf16x8 af[4], bfv[4];
#pragma unroll
      for (int mi = 0; mi < 4; ++mi)
        af[mi] = ld8s(&As[cur][(wm * 64 + mi * 16 + lr) * 64 + ((((kk << 2) + lg) ^ keyA) << 3)]);
#pragma unroll
      for (int ni = 0; ni < 4; ++ni)
        bfv[ni] = ld8s(&Bs[cur][(wn * 64 + ni * 16 + lr) * 64 + ((((kk << 2) + lg) ^ keyA) << 3)]);
#pragma unroll
      for (int mi = 0; mi < 4; ++mi)
#pragma unroll
        for (int ni = 0; ni < 4; ++ni)
          acc[mi][ni] = __builtin_amdgcn_mfma_f32_16x16x32_bf16(af[mi], bfv[ni], acc[mi][ni], 0, 0, 0);
    }
    __builtin_amdgcn_s_setprio(0);
    __builtin_amdgcn_sched_barrier(0);
    __builtin_amdgcn_s_barrier();
    if (ti + 2 < nk) {
      stage(cur, (ti + 2) << 6);
      asm volatile("s_waitcnt vmcnt(8)" ::: "memory");
    } else {
      asm volatile("s_waitcnt vmcnt(0)" ::: "memory");
    }
    __builtin_amdgcn_sched_barrier(0);
    __builtin_amdgcn_s_barrier();
    cur ^= 1;
  }

#pragma unroll
  for (int mi = 0; mi < 4; ++mi) {
    int rowb = row0 + wm * 64 + mi * 16 + lg * 4;
    if (EPI == 2) {
#pragma unroll
      for (int p = 0; p < 2; ++p) {
        int colA = n0 + wn * 64 + p * 32 + lr;
        int colG = colA + 16;
        int ocol = ((n0 + wn * 64) >> 1) + p * 16 + lr;
#pragma unroll
        for (int r = 0; r < 4; ++r) {
          int grow = rowb + r;
          float av = acc[mi][2 * p][r] + bias[colA];
          float gv = acc[mi][2 * p + 1][r] + bias[colG];
          ((u16*)Cv)[(size_t)grow * ldc + ocol] = f2bf(av * geluf(gv));
        }
      }
    } else {
#pragma unroll
      for (int ni = 0; ni < 4; ++ni) {
        int gcol = n0 + wn * 64 + ni * 16 + lr;
#pragma unroll
        for (int r = 0; r < 4; ++r) {
          int grow = rowb + r;
          if (GUARD && grow >= M) continue;
          float v = acc[mi][ni][r];
          if (EPI == 0)
            ((u16*)Cv)[(size_t)grow * ldc + gcol] = f2bf(v);
          else
            ((float*)Cv)[(size_t)grow * ldc + gcol] =
                v + bias[gcol] + res[(size_t)grow * ldc + gcol];
        }
      }
    }
  }
}

// ---------- fused attention: swapped-operand QK^T/PV, no-max softmax ----------
// NS q-sets per wave; NS=2 is the proven config (round 8: 91 us attn1).
template <bool TG, int NS>
__global__ __launch_bounds__(256) void attn_kernel(
    const u16* __restrict__ Q, int qs, int qoff,
    const u16* __restrict__ KV, int kvs, int koff, int voff,
    int m, u16* __restrict__ O) {
  int b = blockIdx.z, h = blockIdx.y;
  int t = threadIdx.x;
  int l = t & 63, w = t >> 6;
  int lr = l & 15, lg = l >> 4;
  int q0 = blockIdx.x * (64 * NS) + w * 16;
  __shared__ __align__(16) u16 Ks[2][64 * 64];
  __shared__ __align__(16) u16 Vt[2][64 * 64];
  __shared__ __align__(16) u16 Pl[4][16 * 64];

  bf16x8 qf[NS][2];
#pragma unroll
  for (int s2 = 0; s2 < NS; ++s2) {
    const u16* qrow = Q + (size_t)((b << 11) + q0 + 64 * s2 + lr) * qs + qoff + h * 64;
    qf[s2][0] = ld8s(qrow + lg * 8);
    qf[s2][1] = ld8s(qrow + 32 + lg * 8);
  }

  f32x4 o[NS][4];
  float ps[NS];
#pragma unroll
  for (int s2 = 0; s2 < NS; ++s2) {
    ps[s2] = 0.f;
#pragma unroll
    for (int r = 0; r < 4; ++r) o[s2][r] = f32x4{0.f, 0.f, 0.f, 0.f};
  }

  const u16* kvb = KV + (size_t)b * m * kvs + h * 64;
  int kj = t >> 3, kc = t & 7;
  int srcsw = ((l & 7) ^ (l >> 3)) << 3;
  int psw = (lr & 7) ^ ((lr & 8) >> 1);

  {
#pragma unroll
    for (int q2 = 0; q2 < 2; ++q2) {
      int gr = w * 16 + q2 * 8 + (l >> 3);
      if (TG) { if (gr > m - 1) gr = m - 1; }
      gload16(kvb + (size_t)gr * kvs + koff + srcsw, &Ks[0][(w * 16 + q2 * 8) * 64]);
    }
    int jv = kj * 2;
    int gv0 = jv, gv1 = jv + 1;
    if (TG) { if (gv0 > m - 1) gv0 = m - 1; if (gv1 > m - 1) gv1 = m - 1; }
    uint4 va = *reinterpret_cast<const uint4*>(kvb + (size_t)gv0 * kvs + voff + kc * 8);
    uint4 vb2 = *reinterpret_cast<const uint4*>(kvb + (size_t)gv1 * kvs + voff + kc * 8);
    const u16* vap = reinterpret_cast<const u16*>(&va);
    const u16* vbp = reinterpret_cast<const u16*>(&vb2);
    int jb = jv >> 3, jlow = jv & 7;
#pragma unroll
    for (int i = 0; i < 8; ++i) {
      int d = kc * 8 + i;
      int key = (d ^ (d >> 3)) & 7;
      uint32_t pk = (uint32_t)vap[i] | ((uint32_t)vbp[i] << 16);
      *reinterpret_cast<uint32_t*>(&Vt[0][d * 64 + ((jb ^ key) << 3) + jlow]) = pk;
    }
  }
  __syncthreads();

  int nj = (m + 63) >> 6;
  int cur = 0;
  for (int jt = 0; jt < nj; ++jt) {
    int j0 = jt << 6;
    bool hn = (jt + 1 < nj);
    uint4 va, vb2;
    if (hn) {
      int j0n = j0 + 64;
#pragma unroll
      for (int q2 = 0; q2 < 2; ++q2) {
        int gr = j0n + w * 16 + q2 * 8 + (l >> 3);
        if (TG) { if (gr > m - 1) gr = m - 1; }
        gload16(kvb + (size_t)gr * kvs + koff + srcsw, &Ks[cur ^ 1][(w * 16 + q2 * 8) * 64]);
      }
      int jv = kj * 2;
      int gv0 = j0n + jv, gv1 = j0n + jv + 1;
      if (TG) { if (gv0 > m - 1) gv0 = m - 1; if (gv1 > m - 1) gv1 = m - 1; }
      va = *reinterpret_cast<const uint4*>(kvb + (size_t)gv0 * kvs + voff + kc * 8);
      vb2 = *reinterpret_cast<const uint4*>(kvb + (size_t)gv1 * kvs + voff + kc * 8);
    }

    const u16* Kb = Ks[cur];
    f32x4 sv[NS][4];
#pragma unroll
    for (int c = 0; c < 4; ++c) {
      bf16x8 k0 = ld8s(&Kb[(c * 16 + lr) * 64 + ((lg ^ (lr & 7)) << 3)]);
      bf16x8 k1 = ld8s(&Kb[(c * 16 + lr) * 64 + (((4 + lg) ^ (lr & 7)) << 3)]);
#pragma unroll
      for (int s2 = 0; s2 < NS; ++s2) {
        f32x4 z = f32x4{0.f, 0.f, 0.f, 0.f};
        z = __builtin_amdgcn_mfma_f32_16x16x32_bf16(k0, qf[s2][0], z, 0, 0, 0);
        sv[s2][c] = __builtin_amdgcn_mfma_f32_16x16x32_bf16(k1, qf[s2][1], z, 0, 0, 0);
      }
    }

    if (hn) {
      const u16* vap = reinterpret_cast<const u16*>(&va);
      const u16* vbp = reinterpret_cast<const u16*>(&vb2);
      int jv = kj * 2;
      int jb = jv >> 3, jlow = jv & 7;
#pragma unroll
      for (int i = 0; i < 8; ++i) {
        int d = kc * 8 + i;
        int key = (d ^ (d >> 3)) & 7;
        uint32_t pk = (uint32_t)vap[i] | ((uint32_t)vbp[i] << 16);
        *reinterpret_cast<uint32_t*>(&Vt[cur ^ 1][d * 64 + ((jb ^ key) << 3) + jlow]) = pk;
      }
    }

    bool tail = TG && (j0 + 64 > m);
    const u16* Vb = Vt[cur];
    bf16x8 vfr[2][4];

#pragma unroll
    for (int s2 = 0; s2 < NS; ++s2) {
      uint32_t pk[8];
#pragma unroll
      for (int c = 0; c < 4; ++c) {
        float p[4];
#pragma unroll
        for (int r = 0; r < 4; ++r) {
          float v = exp2f(sv[s2][c][r]);
          if (tail && (j0 + c * 16 + lg * 4 + r >= m)) v = 0.f;
          p[r] = v; ps[s2] += v;
        }
        pk[2 * c] = cvtpk(p[0], p[1]);
        pk[2 * c + 1] = cvtpk(p[2], p[3]);
      }
#pragma unroll
      for (int c = 0; c < 4; ++c) {
        int phys = (2 * c + (lg >> 1)) ^ psw;
        uint2 u; u.x = pk[2 * c]; u.y = pk[2 * c + 1];
        *reinterpret_cast<uint2*>(&Pl[w][lr * 64 + (phys << 3) + ((lg & 1) << 2)]) = u;
      }
#pragma unroll
      for (int ks = 0; ks < 2; ++ks) {
        int physp = (ks * 4 + lg) ^ psw;
        bf16x8 pb = ld8s(&Pl[w][lr * 64 + (physp << 3)]);
#pragma unroll
        for (int dt = 0; dt < 4; ++dt) {
          if (s2 == 0) {
            int d = dt * 16 + lr;
            int key = (d ^ (d >> 3)) & 7;
            vfr[ks][dt] = ld8s(&Vb[d * 64 + ((((ks << 2) + lg) ^ key) << 3)]);
          }
          o[s2][dt] = __builtin_amdgcn_mfma_f32_16x16x32_bf16(vfr[ks][dt], pb, o[s2][dt], 0, 0, 0);
        }
      }
    }
    __syncthreads();
    cur ^= 1;
  }

#pragma unroll
  for (int s2 = 0; s2 < NS; ++s2) {
    ps[s2] += __shfl_xor(ps[s2], 16, 64);
    ps[s2] += __shfl_xor(ps[s2], 32, 64);
    float inv = 1.f / ps[s2];
    int grow = (b << 11) + q0 + 64 * s2 + lr;
    u16* op = O + (size_t)grow * 1024 + h * 64 + lg * 4;
#pragma unroll
    for (int dt = 0; dt < 4; ++dt) {
      uint2 u;
      u.x = cvtpk(o[s2][dt][0] * inv, o[s2][dt][1] * inv);
      u.y = cvtpk(o[s2][dt][2] * inv, o[s2][dt][3] * inv);
      *reinterpret_cast<uint2*>(op + dt * 16) = u;
    }
  }
}

extern "C" void kernel_launch(void* const* d_in, const int* in_sizes, int n_in,
                              void* d_out, int out_size, void* d_ws, size_t ws_size,
                              hipStream_t stream) {
  const float* x_in = (const float*)d_in[0];
  const float* ctx_in = (const float*)d_in[1];
  const float* hint_in = (const float*)d_in[2];
  const float* ln1g = (const float*)d_in[3]; const float* ln1b = (const float*)d_in[4];
  const float* ln2g = (const float*)d_in[5]; const float* ln2b = (const float*)d_in[6];
  const float* ln3g = (const float*)d_in[7]; const float* ln3b = (const float*)d_in[8];
  const float* ln4g = (const float*)d_in[9]; const float* ln4b = (const float*)d_in[10];
  const float* a1wq = (const float*)d_in[11]; const float* a1wk = (const float*)d_in[12];
  const float* a1wv = (const float*)d_in[13]; const float* a1wo = (const float*)d_in[14];
  const float* a1bo = (const float*)d_in[15];
  const float* a2wq = (const float*)d_in[16]; const float* a2wk = (const float*)d_in[17];
  const float* a2wv = (const float*)d_in[18]; const float* a2wo = (const float*)d_in[19];
  const float* a2bo = (const float*)d_in[20];
  const float* a3wq = (const float*)d_in[21]; const float* a3wk = (const float*)d_in[22];
  const float* a3wv = (const float*)d_in[23]; const float* a3wo = (const float*)d_in[24];
  const float* a3bo = (const float*)d_in[25];
  const float* ffw1 = (const float*)d_in[26]; const float* ffb1 = (const float*)d_in[27];
  const float* ffw2 = (const float*)d_in[28]; const float* ffb2 = (const float*)d_in[29];

  char* wsb = (char*)d_ws;
  size_t off = 0;
  auto alloc = [&](size_t bytes) -> void* {
    void* p = wsb + off;
    off += (bytes + 255) & ~(size_t)255;
    return p;
  };
  u16* wqkv1t = (u16*)alloc(3072ull * 1024 * 2);
  u16* wo1t = (u16*)alloc(1024ull * 1024 * 2);
  u16* wq2t = (u16*)alloc(1024ull * 1024 * 2);
  u16* wkv2t = (u16*)alloc(2048ull * 1024 * 2);
  u16* wo2t = (u16*)alloc(1024ull * 1024 * 2);
  u16* wq3t = (u16*)alloc(1024ull * 1024 * 2);
  u16* wkv3t = (u16*)alloc(2048ull * 1024 * 2);
  u16* wo3t = (u16*)alloc(1024ull * 1024 * 2);
  u16* w1t = (u16*)alloc(8192ull * 1024 * 2);
  u16* w2t = (u16*)alloc(1024ull * 4096 * 2);
  float* b1p = (float*)alloc(8192ull * 4);
  u16* hintbf = (u16*)alloc(500ull * 1024 * 2);
  u16* ctxbf = (u16*)alloc(512ull * 1024 * 2);
  float* xbuf = (float*)alloc(4096ull * 1024 * 4);
  u16* hbf = (u16*)alloc(4096ull * 1024 * 2);
  u16* attnout = (u16*)alloc(4096ull * 1024 * 2);
  u16* qbuf = (u16*)alloc(4096ull * 1024 * 2);
  u16* kvbuf = (u16*)alloc(512ull * 2048 * 2);
  u16* qkv = (u16*)alloc(4096ull * 4096 * 2);  // union: qkv [4096][3072] / g [4096][4096]
  u16* gbuf = qkv;

  // ---- batched weight/activation prep: one launch ----
  PrepArgs pa;
  int bi = 0, bc = 0;
  auto addJ = [&](const void* s, void* d, int K, int N, int mode, int roff,
                  int ldo, int slo, int shi, int nblk) {
    pa.j[bi].src = s; pa.j[bi].dst = d; pa.j[bi].K = K; pa.j[bi].N = N;
    pa.j[bi].mode = mode; pa.j[bi].row_off = roff; pa.j[bi].ldo = ldo;
    pa.j[bi].s_lo = slo; pa.j[bi].s_hi = shi; pa.j[bi].blk0 = bc;
    bc += nblk; ++bi;
  };
  addJ(a1wq, wqkv1t, 1024, 1024, 0, 0, 1024, 0, 1024, 1024);     // scaled (Q)
  addJ(a1wk, wqkv1t, 1024, 1024, 0, 1024, 1024, 0, 0, 1024);
  addJ(a1wv, wqkv1t, 1024, 1024, 0, 2048, 1024, 0, 0, 1024);
  addJ(a1wo, wo1t, 1024, 1024, 0, 0, 1024, 0, 0, 1024);
  addJ(a2wq, wq2t, 1024, 1024, 0, 0, 1024, 0, 1024, 1024);       // scaled (Q)
  addJ(a2wk, wkv2t, 1024, 1024, 0, 0, 1024, 0, 0, 1024);
  addJ(a2wv, wkv2t, 1024, 1024, 0, 1024, 1024, 0, 0, 1024);
  addJ(a2wo, wo2t, 1024, 1024, 0, 0, 1024, 0, 0, 1024);
  addJ(a3wq, wq3t, 1024, 1024, 0, 0, 1024, 0, 1024, 1024);       // scaled (Q)
  addJ(a3wk, wkv3t, 1024, 1024, 0, 0, 1024, 0, 0, 1024);
  addJ(a3wv, wkv3t, 1024, 1024, 0, 1024, 1024, 0, 0, 1024);
  addJ(a3wo, wo3t, 1024, 1024, 0, 0, 1024, 0, 0, 1024);
  addJ(ffw1, w1t, 1024, 8192, 1, 0, 1024, 0, 0, 8192);
  addJ(ffw2, w2t, 4096, 1024, 0, 0, 4096, 0, 0, 4096);
  addJ(ctx_in, ctxbf, 0, 0, 2, 0, 0, 0, 0, 512);
  addJ(hint_in, hintbf, 0, 0, 3, 0, 0, 0, 0, 500);
  addJ(ffb1, b1p, 0, 0, 4, 0, 0, 0, 0, 32);
  wprep_kernel<<<bc, 256, 0, stream>>>(pa);

  // ---- stage 1: self-attention ----
  ln_kernel<<<4096, 256, 0, stream>>>(x_in, ln1g, ln1b, hbf);
  gemm_bt_kernel<0, false><<<dim3(24, 32), 256, 0, stream>>>(hbf, 1024, wqkv1t, qkv, 3072,
                                                             nullptr, nullptr, 4096, 3072, 1024);
  attn_kernel<false, 2><<<dim3(16, 16, 2), 256, 0, stream>>>(
      qkv, 3072, 0, qkv, 3072, 1024, 2048, 2048, attnout);
  gemm64_kernel<1><<<dim3(16, 32), 256, 0, stream>>>(attnout, 1024, wo1t, xbuf, 1024,
                                                     a1bo, x_in, 4096, 1024, 1024);

  // ---- stage 2: cross-attention over context ----
  ln_kernel<<<4096, 256, 0, stream>>>(xbuf, ln2g, ln2b, hbf);
  gemm64_kernel<0><<<dim3(16, 32), 256, 0, stream>>>(hbf, 1024, wq2t, qbuf, 1024,
                                                     nullptr, nullptr, 4096, 1024, 1024);
  gemm_bt_kernel<0, false><<<dim3(16, 4), 256, 0, stream>>>(ctxbf, 1024, wkv2t, kvbuf, 2048,
                                                            nullptr, nullptr, 512, 2048, 1024);
  attn_kernel<false, 2><<<dim3(16, 16, 2), 256, 0, stream>>>(
      qbuf, 1024, 0, kvbuf, 2048, 0, 1024, 256, attnout);
  gemm64_kernel<1><<<dim3(16, 32), 256, 0, stream>>>(attnout, 1024, wo2t, xbuf, 1024,
                                                     a2bo, xbuf, 4096, 1024, 1024);

  // ---- stage 3: video cross-attention (uses ln4) ----
  ln_kernel<<<4096, 256, 0, stream>>>(xbuf, ln4g, ln4b, hbf);
  gemm64_kernel<0><<<dim3(16, 32), 256, 0, stream>>>(hbf, 1024, wq3t, qbuf, 1024,
                                                     nullptr, nullptr, 4096, 1024, 1024);
  gemm_bt_kernel<0, true><<<dim3(16, 4), 256, 0, stream>>>(hintbf, 1024, wkv3t, kvbuf, 2048,
                                                           nullptr, nullptr, 500, 2048, 1024);
  attn_kernel<true, 2><<<dim3(16, 16, 2), 256, 0, stream>>>(
      qbuf, 1024, 0, kvbuf, 2048, 0, 1024, 250, attnout);
  gemm64_kernel<1><<<dim3(16, 32), 256, 0, stream>>>(attnout, 1024, wo3t, xbuf, 1024,
                                                     a3bo, xbuf, 4096, 1024, 1024);

  // ---- GEGLU feed-forward (uses ln3) ----
  ln_kernel<<<4096, 256, 0, stream>>>(xbuf, ln3g, ln3b, hbf);
  gemm_bt_kernel<2, false><<<dim3(64, 32), 256, 0, stream>>>(hbf, 1024, w1t, gbuf, 4096,
                                                             b1p, nullptr, 4096, 8192, 1024);
  gemm64_kernel<1><<<dim3(16, 32), 256, 0, stream>>>(gbuf, 4096, w2t, d_out, 1024,
                                                     ffb2, xbuf, 4096, 1024, 4096);
}

// Round 13
// 473.999 us; speedup vs baseline: 1.0351x; 1.0351x over previous
//
#include <hip/hip_runtime.h>
#include <cstdint>

typedef unsigned short u16;
typedef __bf16 bf16x8 __attribute__((ext_vector_type(8)));
typedef float f32x4 __attribute__((ext_vector_type(4)));

__device__ __forceinline__ u16 f2bf(float f) {
  union { float f; uint32_t u; } x; x.f = f;
  uint32_t r = x.u + 0x7FFFu + ((x.u >> 16) & 1u);
  return (u16)(r >> 16);
}
__device__ __forceinline__ bf16x8 ld8s(const u16* p) {
  return *reinterpret_cast<const bf16x8*>(p);
}
__device__ __forceinline__ float geluf(float x) {
  return 0.5f * x * (1.f + erff(x * 0.70710678118654752f));
}
__device__ __forceinline__ uint32_t cvtpk(float a, float b) {
  uint32_t r;
  asm("v_cvt_pk_bf16_f32 %0, %1, %2" : "=v"(r) : "v"(a), "v"(b));
  return r;
}
// async global->LDS, 16B per lane; lds dest must be wave-uniform base (+lane*16)
__device__ __forceinline__ void gload16(const u16* g, u16* l) {
  __builtin_amdgcn_global_load_lds(
      (__attribute__((address_space(1))) void*)const_cast<u16*>(g),
      (__attribute__((address_space(3))) void*)l, 16, 0, 0);
}

// ---------- batched weight prep: all transposes/converts in ONE launch ----------
struct PrepJob {
  const void* src; void* dst;
  int K, N, mode, row_off, ldo, s_lo, s_hi, blk0;
};
struct PrepArgs { PrepJob j[17]; };

__global__ __launch_bounds__(256) void wprep_kernel(PrepArgs a) {
  __shared__ float tile[32][33];
  int bid = blockIdx.x;
  int t = threadIdx.x;
  const float* src = nullptr; void* dst = nullptr;
  int K = 0, N = 0, mode = 0, roff = 0, ldo = 0, slo = 0, shi = 0, bl = 0;
#pragma unroll
  for (int i = 0; i < 17; ++i) {
    int lo = a.j[i].blk0;
    int hi = (i == 16) ? 0x7fffffff : a.j[i + 1].blk0;
    if (bid >= lo && bid < hi) {
      src = (const float*)a.j[i].src; dst = a.j[i].dst;
      K = a.j[i].K; N = a.j[i].N; mode = a.j[i].mode; roff = a.j[i].row_off;
      ldo = a.j[i].ldo; slo = a.j[i].s_lo; shi = a.j[i].s_hi; bl = bid - lo;
    }
  }
  (void)K;
  if (mode <= 1) {
    int nb = N >> 5;
    int bx = bl % nb, by = bl / nb;
    int tx = t & 31, ty = t >> 5;
    int n = bx * 32 + tx, kbase = by * 32;
#pragma unroll
    for (int r = 0; r < 4; ++r)
      tile[ty + r * 8][tx] = src[(size_t)(kbase + ty + r * 8) * N + n];
    __syncthreads();
#pragma unroll
    for (int r = 0; r < 4; ++r) {
      int nl = ty + r * 8, ng = bx * 32 + nl;
      int orow;
      if (mode == 0) orow = roff + ng;
      else {
        if (ng < 4096) orow = ((ng >> 4) << 5) + (ng & 15);
        else { int t2 = ng - 4096; orow = ((t2 >> 4) << 5) + 16 + (t2 & 15); }
      }
      float v = tile[tx][nl];
      if (mode == 0 && orow >= slo && orow < shi) v *= 0.18033688011112042f;  // 0.125*log2e
      ((u16*)dst)[(size_t)orow * ldo + kbase + tx] = f2bf(v);
    }
  } else if (mode == 2) {
    int idx = bl * 1024 + t * 4;
    float4 v = *reinterpret_cast<const float4*>(src + idx);
    ushort4 o;
    o.x = f2bf(v.x); o.y = f2bf(v.y); o.z = f2bf(v.z); o.w = f2bf(v.w);
    *reinterpret_cast<ushort4*>((u16*)dst + idx) = o;
  } else if (mode == 3) {
    int row = bl;
    int tt = row % 250;
    int d0 = t * 4;
    int i0 = d0 >> 1;
    float den0 = powf(10000.f, (float)i0 / 512.f);
    float den1 = powf(10000.f, (float)(i0 + 1) / 512.f);
    float a0 = (float)tt / den0, a1 = (float)tt / den1;
    const float* hp = src + (size_t)row * 1024 + d0;
    u16* op = (u16*)dst + (size_t)row * 1024 + d0;
    op[0] = f2bf(hp[0] + sinf(a0));
    op[1] = f2bf(hp[1] + cosf(a0));
    op[2] = f2bf(hp[2] + sinf(a1));
    op[3] = f2bf(hp[3] + cosf(a1));
  } else {
    int i2 = bl * 256 + t;
    int g = i2 >> 5, s2 = i2 & 31;
    int c2 = (s2 < 16) ? (g * 16 + s2) : (4096 + g * 16 + (s2 - 16));
    ((float*)dst)[i2] = src[c2];
  }
}

// ---------- LayerNorm: f32 [rows][1024] -> bf16 ----------
__global__ __launch_bounds__(256) void ln_kernel(const float* __restrict__ x,
                                                 const float* __restrict__ g,
                                                 const float* __restrict__ b,
                                                 u16* __restrict__ out) {
  int row = blockIdx.x;
  int tid = threadIdx.x;
  int l = tid & 63, w = tid >> 6;
  const float4 v = reinterpret_cast<const float4*>(x + (size_t)row * 1024)[tid];
  float s = v.x + v.y + v.z + v.w;
#pragma unroll
  for (int d = 1; d < 64; d <<= 1) s += __shfl_xor(s, d, 64);
  __shared__ float red[8];
  if (l == 0) red[w] = s;
  __syncthreads();
  float mean = (red[0] + red[1] + red[2] + red[3]) * (1.f / 1024.f);
  float dx = v.x - mean, dy = v.y - mean, dz = v.z - mean, dw = v.w - mean;
  float vs = dx * dx + dy * dy + dz * dz + dw * dw;
#pragma unroll
  for (int d = 1; d < 64; d <<= 1) vs += __shfl_xor(vs, d, 64);
  if (l == 0) red[4 + w] = vs;
  __syncthreads();
  float var = (red[4] + red[5] + red[6] + red[7]) * (1.f / 1024.f);
  float rstd = rsqrtf(var + 1e-5f);
  const float4 g4 = reinterpret_cast<const float4*>(g)[tid];
  const float4 b4 = reinterpret_cast<const float4*>(b)[tid];
  ushort4 o;
  o.x = f2bf(dx * rstd * g4.x + b4.x);
  o.y = f2bf(dy * rstd * g4.y + b4.y);
  o.z = f2bf(dz * rstd * g4.z + b4.z);
  o.w = f2bf(dw * rstd * g4.w + b4.w);
  reinterpret_cast<ushort4*>(out + (size_t)row * 1024)[tid] = o;
}

// ---------- 256x256 8-phase GEMM (round-11 proven: ff1 91us / qkv1) ----------
template <int EPI>
__global__ __launch_bounds__(512, 2) void gemm256_kernel(
    const u16* __restrict__ A, int lda, const u16* __restrict__ Bt,
    void* __restrict__ Cv, int ldc, const float* __restrict__ bias,
    int M, int N, int K) {
  __shared__ __align__(16) u16 As[2][256 * 64];
  __shared__ __align__(16) u16 Bs[2][256 * 64];
  int t = threadIdx.x;
  int l = t & 63, w = t >> 6;
  int wm = w >> 2, wn = w & 3;
  int lr = l & 15, lg = l >> 4;
  int gx = gridDim.x;
  int nwg = gx * gridDim.y;
  int orig = blockIdx.y * gx + blockIdx.x;
  int qq = nwg >> 3, rr = nwg & 7;
  int xcd = orig & 7, lin = orig >> 3;
  int wg = (xcd < rr ? xcd * (qq + 1) : rr * (qq + 1) + (xcd - rr) * qq) + lin;
  int bx = wg % gx, by = wg / gx;
  int row0 = by * 256, n0 = bx * 256;

  int lrow8 = l >> 3, lchunk = l & 7;
  int csrc = (lchunk ^ lrow8) * 8;
  int keyA = lr & 7;
  int c0 = ((lg ^ keyA) << 3);
  int c1 = (((4 + lg) ^ keyA) << 3);

  f32x4 acc[8][4];
#pragma unroll
  for (int i = 0; i < 8; ++i)
#pragma unroll
    for (int j = 0; j < 4; ++j) acc[i][j] = f32x4{0.f, 0.f, 0.f, 0.f};

  auto stA = [&](int buf, int k0, int q) {
    int rb = q * 64 + w * 8;
    gload16(&A[(size_t)(row0 + rb + lrow8) * lda + k0 + csrc], &As[buf][rb * 64]);
  };
  auto stB = [&](int buf, int k0, int q) {
    int rb = q * 64 + w * 8;
    gload16(&Bt[(size_t)(n0 + rb + lrow8) * K + k0 + csrc], &Bs[buf][rb * 64]);
  };

  int nk = K >> 6;
  stB(0, 0, 0); stB(0, 0, 1); stB(0, 0, 2); stB(0, 0, 3);
  stA(0, 0, 0); stA(0, 0, 2); stA(0, 0, 1); stA(0, 0, 3);
  asm volatile("s_waitcnt vmcnt(2)" ::: "memory");
  __builtin_amdgcn_sched_barrier(0);
  asm volatile("s_barrier" ::: "memory");

  for (int ti = 0; ti < nk; ++ti) {
    int cur = ti & 1, nxt = cur ^ 1;
    bool hn = (ti + 1 < nk);
    int k0n = (ti + 1) << 6;
    const u16* Ab = As[cur];
    const u16* Bb = Bs[cur];
    bf16x8 a[4], b[4];

#pragma unroll
    for (int mi = 0; mi < 4; ++mi) a[mi] = ld8s(&Ab[(wm * 128 + mi * 16 + lr) * 64 + c0]);
#pragma unroll
    for (int ni = 0; ni < 4; ++ni) b[ni] = ld8s(&Bb[(wn * 64 + ni * 16 + lr) * 64 + c0]);
    if (hn) { stB(nxt, k0n, 0); stB(nxt, k0n, 1); }
    asm volatile("s_barrier" ::: "memory");
    __builtin_amdgcn_s_setprio(1);
#pragma unroll
    for (int mi = 0; mi < 4; ++mi)
#pragma unroll
      for (int ni = 0; ni < 4; ++ni)
        acc[mi][ni] = __builtin_amdgcn_mfma_f32_16x16x32_bf16(a[mi], b[ni], acc[mi][ni], 0, 0, 0);
    __builtin_amdgcn_s_setprio(0);
    if (hn) asm volatile("s_waitcnt vmcnt(2)" ::: "memory");
    else    asm volatile("s_waitcnt vmcnt(0)" ::: "memory");
    __builtin_amdgcn_sched_barrier(0);
    asm volatile("s_barrier" ::: "memory");

#pragma unroll
    for (int mi = 0; mi < 4; ++mi) a[mi] = ld8s(&Ab[(wm * 128 + (mi + 4) * 16 + lr) * 64 + c0]);
    if (hn) { stB(nxt, k0n, 2); stB(nxt, k0n, 3); }
    asm volatile("s_barrier" ::: "memory");
    __builtin_amdgcn_s_setprio(1);
#pragma unroll
    for (int mi = 0; mi < 4; ++mi)
#pragma unroll
      for (int ni = 0; ni < 4; ++ni)
        acc[mi + 4][ni] = __builtin_amdgcn_mfma_f32_16x16x32_bf16(a[mi], b[ni], acc[mi + 4][ni], 0, 0, 0);
    __builtin_amdgcn_s_setprio(0);
    asm volatile("s_barrier" ::: "memory");

#pragma unroll
    for (int mi = 0; mi < 4; ++mi) a[mi] = ld8s(&Ab[(wm * 128 + mi * 16 + lr) * 64 + c1]);
#pragma unroll
    for (int ni = 0; ni < 4; ++ni) b[ni] = ld8s(&Bb[(wn * 64 + ni * 16 + lr) * 64 + c1]);
    if (hn) { stA(nxt, k0n, 0); stA(nxt, k0n, 2); }
    asm volatile("s_barrier" ::: "memory");
    __builtin_amdgcn_s_setprio(1);
#pragma unroll
    for (int mi = 0; mi < 4; ++mi)
#pragma unroll
      for (int ni = 0; ni < 4; ++ni)
        acc[mi][ni] = __builtin_amdgcn_mfma_f32_16x16x32_bf16(a[mi], b[ni], acc[mi][ni], 0, 0, 0);
    __builtin_amdgcn_s_setprio(0);
    asm volatile("s_barrier" ::: "memory");

#pragma unroll
    for (int mi = 0; mi < 4; ++mi) a[mi] = ld8s(&Ab[(wm * 128 + (mi + 4) * 16 + lr) * 64 + c1]);
    if (hn) { stA(nxt, k0n, 1); stA(nxt, k0n, 3); }
    asm volatile("s_barrier" ::: "memory");
    __builtin_amdgcn_s_setprio(1);
#pragma unroll
    for (int mi = 0; mi < 4; ++mi)
#pragma unroll
      for (int ni = 0; ni < 4; ++ni)
        acc[mi + 4][ni] = __builtin_amdgcn_mfma_f32_16x16x32_bf16(a[mi], b[ni], acc[mi + 4][ni], 0, 0, 0);
    __builtin_amdgcn_s_setprio(0);
    if (hn) asm volatile("s_waitcnt vmcnt(2)" ::: "memory");
    __builtin_amdgcn_sched_barrier(0);
    asm volatile("s_barrier" ::: "memory");
  }

#pragma unroll
  for (int mi = 0; mi < 8; ++mi) {
    int rowb = row0 + wm * 128 + mi * 16 + lg * 4;
    if (EPI == 2) {
#pragma unroll
      for (int p = 0; p < 2; ++p) {
        int colA = n0 + wn * 64 + p * 32 + lr;
        int colG = colA + 16;
        int ocol = ((n0 + wn * 64) >> 1) + p * 16 + lr;
#pragma unroll
        for (int r = 0; r < 4; ++r) {
          float av = acc[mi][2 * p][r] + bias[colA];
          float gv = acc[mi][2 * p + 1][r] + bias[colG];
          ((u16*)Cv)[(size_t)(rowb + r) * ldc + ocol] = f2bf(av * geluf(gv));
        }
      }
    } else {
#pragma unroll
      for (int ni = 0; ni < 4; ++ni) {
        int gcol = n0 + wn * 64 + ni * 16 + lr;
#pragma unroll
        for (int r = 0; r < 4; ++r)
          ((u16*)Cv)[(size_t)(rowb + r) * ldc + gcol] = f2bf(acc[mi][ni][r]);
      }
    }
  }
}

// ---------- GEMM 128x64 pipelined (counted vmcnt, dbuf, 3 blocks/CU) ----------
template <int EPI>
__global__ __launch_bounds__(256) void gemm64_kernel(
    const u16* __restrict__ A, int lda, const u16* __restrict__ Bt,
    void* __restrict__ Cv, int ldc, const float* __restrict__ bias,
    const float* __restrict__ res, int M, int N, int K) {
  __shared__ __align__(16) u16 As[2][128 * 64];
  __shared__ __align__(16) u16 Bs[2][64 * 64];
  int t = threadIdx.x;
  int l = t & 63, w = t >> 6;
  int wm = w >> 1, wn = w & 1;
  int lr = l & 15, lg = l >> 4;
  int gx = gridDim.x;
  int nwg = gx * gridDim.y;
  int orig = blockIdx.y * gx + blockIdx.x;
  int qq = nwg >> 3, rr = nwg & 7;
  int xcd = orig & 7, lin = orig >> 3;
  int wg = (xcd < rr ? xcd * (qq + 1) : rr * (qq + 1) + (xcd - rr) * qq) + lin;
  int bx = wg % gx, by = wg / gx;
  int row0 = by * 128, n0 = bx * 64;

  int lrow8 = l >> 3, lchunk = l & 7;
  int csrc = (lchunk ^ lrow8) * 8;
  int keyA = lr & 7;
  f32x4 acc[4][2];
#pragma unroll
  for (int i = 0; i < 4; ++i)
#pragma unroll
    for (int j = 0; j < 2; ++j) acc[i][j] = f32x4{0.f, 0.f, 0.f, 0.f};

  auto stage = [&](int buf, int k0) {
#pragma unroll
    for (int q = 0; q < 4; ++q) {
      int rb = q * 32 + w * 8;
      gload16(&A[(size_t)(row0 + rb + lrow8) * lda + k0 + csrc], &As[buf][rb * 64]);
    }
#pragma unroll
    for (int q = 0; q < 2; ++q) {
      int rb = q * 32 + w * 8;
      gload16(&Bt[(size_t)(n0 + rb + lrow8) * K + k0 + csrc], &Bs[buf][rb * 64]);
    }
  };

  int nk = K >> 6;
  stage(0, 0);
  if (nk > 1) {
    stage(1, 64);
    asm volatile("s_waitcnt vmcnt(6)" ::: "memory");
  } else {
    asm volatile("s_waitcnt vmcnt(0)" ::: "memory");
  }
  __builtin_amdgcn_sched_barrier(0);
  __builtin_amdgcn_s_barrier();
  int cur = 0;
  for (int ti = 0; ti < nk; ++ti) {
    __builtin_amdgcn_s_setprio(1);
#pragma unroll
    for (int kk = 0; kk < 2; ++kk) {
      bf16x8 af[4], bfv[2];
#pragma unroll
      for (int mi = 0; mi < 4; ++mi)
        af[mi] = ld8s(&As[cur][(wm * 64 + mi * 16 + lr) * 64 + ((((kk << 2) + lg) ^ keyA) << 3)]);
#pragma unroll
      for (int ni = 0; ni < 2; ++ni)
        bfv[ni] = ld8s(&Bs[cur][(wn * 32 + ni * 16 + lr) * 64 + ((((kk << 2) + lg) ^ keyA) << 3)]);
#pragma unroll
      for (int mi = 0; mi < 4; ++mi)
#pragma unroll
        for (int ni = 0; ni < 2; ++ni)
          acc[mi][ni] = __builtin_amdgcn_mfma_f32_16x16x32_bf16(af[mi], bfv[ni], acc[mi][ni], 0, 0, 0);
    }
    __builtin_amdgcn_s_setprio(0);
    __builtin_amdgcn_sched_barrier(0);
    __builtin_amdgcn_s_barrier();
    if (ti + 2 < nk) {
      stage(cur, (ti + 2) << 6);
      asm volatile("s_waitcnt vmcnt(6)" ::: "memory");
    } else {
      asm volatile("s_waitcnt vmcnt(0)" ::: "memory");
    }
    __builtin_amdgcn_sched_barrier(0);
    __builtin_amdgcn_s_barrier();
    cur ^= 1;
  }

#pragma unroll
  for (int mi = 0; mi < 4; ++mi) {
    int rowb = row0 + wm * 64 + mi * 16 + lg * 4;
#pragma unroll
    for (int ni = 0; ni < 2; ++ni) {
      int gcol = n0 + wn * 32 + ni * 16 + lr;
#pragma unroll
      for (int r = 0; r < 4; ++r) {
        int grow = rowb + r;
        float v = acc[mi][ni][r];
        if (EPI == 0)
          ((u16*)Cv)[(size_t)grow * ldc + gcol] = f2bf(v);
        else
          ((float*)Cv)[(size_t)grow * ldc + gcol] =
              v + bias[gcol] + res[(size_t)grow * ldc + gcol];
      }
    }
  }
}

// ---------- GEMM 128x128 pipelined (kv projections only) ----------
template <int EPI, bool GUARD>
__global__ __launch_bounds__(256) void gemm_bt_kernel(
    const u16* __restrict__ A, int lda, const u16* __restrict__ Bt,
    void* __restrict__ Cv, int ldc, const float* __restrict__ bias,
    const float* __restrict__ res, int M, int N, int K) {
  __shared__ __align__(16) u16 As[2][128 * 64];
  __shared__ __align__(16) u16 Bs[2][128 * 64];
  int t = threadIdx.x;
  int l = t & 63, w = t >> 6;
  int wm = w >> 1, wn = w & 1;
  int lr = l & 15, lg = l >> 4;
  int gx = gridDim.x;
  int nwg = gx * gridDim.y;
  int orig = blockIdx.y * gx + blockIdx.x;
  int qq = nwg >> 3, rr = nwg & 7;
  int xcd = orig & 7, lin = orig >> 3;
  int wg = (xcd < rr ? xcd * (qq + 1) : rr * (qq + 1) + (xcd - rr) * qq) + lin;
  int bx = wg % gx, by = wg / gx;
  int row0 = by * 128, n0 = bx * 128;

  int lrow8 = l >> 3, lchunk = l & 7;
  int csrc = (lchunk ^ lrow8) * 8;
  int keyA = lr & 7;
  f32x4 acc[4][4];
#pragma unroll
  for (int i = 0; i < 4; ++i)
#pragma unroll
    for (int j = 0; j < 4; ++j) acc[i][j] = f32x4{0.f, 0.f, 0.f, 0.f};

  auto stage = [&](int buf, int k0) {
#pragma unroll
    for (int q = 0; q < 4; ++q) {
      int rbase = w * 32 + q * 8;
      int r = rbase + lrow8;
      int ga = row0 + r;
      if (GUARD) { if (ga > M - 1) ga = M - 1; }
      gload16(&A[(size_t)ga * lda + k0 + csrc], &As[buf][rbase * 64]);
      gload16(&Bt[(size_t)(n0 + r) * K + k0 + csrc], &Bs[buf][rbase * 64]);
    }
  };

  int nk = K >> 6;
  stage(0, 0);
  if (nk > 1) {
    stage(1, 64);
    asm volatile("s_waitcnt vmcnt(8)" ::: "memory");
  } else {
    asm volatile("s_waitcnt vmcnt(0)" ::: "memory");
  }
  __builtin_amdgcn_sched_barrier(0);
  __builtin_amdgcn_s_barrier();
  int cur = 0;
  for (int ti = 0; ti < nk; ++ti) {
    __builtin_amdgcn_s_setprio(1);
#pragma unroll
    for (int kk = 0; kk < 2; ++kk) {
      bf16x8 af[4], bfv[4];
#pragma unroll
      for (int mi = 0; mi < 4; ++mi)
        af[mi] = ld8s(&As[cur][(wm * 64 + mi * 16 + lr) * 64 + ((((kk << 2) + lg) ^ keyA) << 3)]);
#pragma unroll
      for (int ni = 0; ni < 4; ++ni)
        bfv[ni] = ld8s(&Bs[cur][(wn * 64 + ni * 16 + lr) * 64 + ((((kk << 2) + lg) ^ keyA) << 3)]);
#pragma unroll
      for (int mi = 0; mi < 4; ++mi)
#pragma unroll
        for (int ni = 0; ni < 4; ++ni)
          acc[mi][ni] = __builtin_amdgcn_mfma_f32_16x16x32_bf16(af[mi], bfv[ni], acc[mi][ni], 0, 0, 0);
    }
    __builtin_amdgcn_s_setprio(0);
    __builtin_amdgcn_sched_barrier(0);
    __builtin_amdgcn_s_barrier();
    if (ti + 2 < nk) {
      stage(cur, (ti + 2) << 6);
      asm volatile("s_waitcnt vmcnt(8)" ::: "memory");
    } else {
      asm volatile("s_waitcnt vmcnt(0)" ::: "memory");
    }
    __builtin_amdgcn_sched_barrier(0);
    __builtin_amdgcn_s_barrier();
    cur ^= 1;
  }

#pragma unroll
  for (int mi = 0; mi < 4; ++mi) {
    int rowb = row0 + wm * 64 + mi * 16 + lg * 4;
#pragma unroll
    for (int ni = 0; ni < 4; ++ni) {
      int gcol = n0 + wn * 64 + ni * 16 + lr;
#pragma unroll
      for (int r = 0; r < 4; ++r) {
        int grow = rowb + r;
        if (GUARD && grow >= M) continue;
        float v = acc[mi][ni][r];
        if (EPI == 0)
          ((u16*)Cv)[(size_t)grow * ldc + gcol] = f2bf(v);
        else
          ((float*)Cv)[(size_t)grow * ldc + gcol] =
              v + bias[gcol] + res[(size_t)grow * ldc + gcol];
      }
    }
  }
}

// ---------- fused attention: swapped-operand QK^T/PV, no-max softmax ----------
// NS q-sets per wave; per-set Pl buffers break the inter-set LDS serialization
// (set1's P-write no longer waits on set0's PV reads of the same buffer).
template <bool TG, int NS>
__global__ __launch_bounds__(256) void attn_kernel(
    const u16* __restrict__ Q, int qs, int qoff,
    const u16* __restrict__ KV, int kvs, int koff, int voff,
    int m, u16* __restrict__ O) {
  int b = blockIdx.z, h = blockIdx.y;
  int t = threadIdx.x;
  int l = t & 63, w = t >> 6;
  int lr = l & 15, lg = l >> 4;
  int q0 = blockIdx.x * (64 * NS) + w * 16;
  __shared__ __align__(16) u16 Ks[2][64 * 64];
  __shared__ __align__(16) u16 Vt[2][64 * 64];
  __shared__ __align__(16) u16 Pl[4][NS][16 * 64];

  bf16x8 qf[NS][2];
#pragma unroll
  for (int s2 = 0; s2 < NS; ++s2) {
    const u16* qrow = Q + (size_t)((b << 11) + q0 + 64 * s2 + lr) * qs + qoff + h * 64;
    qf[s2][0] = ld8s(qrow + lg * 8);
    qf[s2][1] = ld8s(qrow + 32 + lg * 8);
  }

  f32x4 o[NS][4];
  float ps[NS];
#pragma unroll
  for (int s2 = 0; s2 < NS; ++s2) {
    ps[s2] = 0.f;
#pragma unroll
    for (int r = 0; r < 4; ++r) o[s2][r] = f32x4{0.f, 0.f, 0.f, 0.f};
  }

  const u16* kvb = KV + (size_t)b * m * kvs + h * 64;
  int kj = t >> 3, kc = t & 7;
  int srcsw = ((l & 7) ^ (l >> 3)) << 3;
  int psw = (lr & 7) ^ ((lr & 8) >> 1);

  {
#pragma unroll
    for (int q2 = 0; q2 < 2; ++q2) {
      int gr = w * 16 + q2 * 8 + (l >> 3);
      if (TG) { if (gr > m - 1) gr = m - 1; }
      gload16(kvb + (size_t)gr * kvs + koff + srcsw, &Ks[0][(w * 16 + q2 * 8) * 64]);
    }
    int jv = kj * 2;
    int gv0 = jv, gv1 = jv + 1;
    if (TG) { if (gv0 > m - 1) gv0 = m - 1; if (gv1 > m - 1) gv1 = m - 1; }
    uint4 va = *reinterpret_cast<const uint4*>(kvb + (size_t)gv0 * kvs + voff + kc * 8);
    uint4 vb2 = *reinterpret_cast<const uint4*>(kvb + (size_t)gv1 * kvs + voff + kc * 8);
    const u16* vap = reinterpret_cast<const u16*>(&va);
    const u16* vbp = reinterpret_cast<const u16*>(&vb2);
    int jb = jv >> 3, jlow = jv & 7;
#pragma unroll
    for (int i = 0; i < 8; ++i) {
      int d = kc * 8 + i;
      int key = (d ^ (d >> 3)) & 7;
      uint32_t pk = (uint32_t)vap[i] | ((uint32_t)vbp[i] << 16);
      *reinterpret_cast<uint32_t*>(&Vt[0][d * 64 + ((jb ^ key) << 3) + jlow]) = pk;
    }
  }
  __syncthreads();

  int nj = (m + 63) >> 6;
  int cur = 0;
  for (int jt = 0; jt < nj; ++jt) {
    int j0 = jt << 6;
    bool hn = (jt + 1 < nj);
    uint4 va, vb2;
    if (hn) {
      int j0n = j0 + 64;
#pragma unroll
      for (int q2 = 0; q2 < 2; ++q2) {
        int gr = j0n + w * 16 + q2 * 8 + (l >> 3);
        if (TG) { if (gr > m - 1) gr = m - 1; }
        gload16(kvb + (size_t)gr * kvs + koff + srcsw, &Ks[cur ^ 1][(w * 16 + q2 * 8) * 64]);
      }
      int jv = kj * 2;
      int gv0 = j0n + jv, gv1 = j0n + jv + 1;
      if (TG) { if (gv0 > m - 1) gv0 = m - 1; if (gv1 > m - 1) gv1 = m - 1; }
      va = *reinterpret_cast<const uint4*>(kvb + (size_t)gv0 * kvs + voff + kc * 8);
      vb2 = *reinterpret_cast<const uint4*>(kvb + (size_t)gv1 * kvs + voff + kc * 8);
    }

    const u16* Kb = Ks[cur];
    f32x4 sv[NS][4];
#pragma unroll
    for (int c = 0; c < 4; ++c) {
      bf16x8 k0 = ld8s(&Kb[(c * 16 + lr) * 64 + ((lg ^ (lr & 7)) << 3)]);
      bf16x8 k1 = ld8s(&Kb[(c * 16 + lr) * 64 + (((4 + lg) ^ (lr & 7)) << 3)]);
#pragma unroll
      for (int s2 = 0; s2 < NS; ++s2) {
        f32x4 z = f32x4{0.f, 0.f, 0.f, 0.f};
        z = __builtin_amdgcn_mfma_f32_16x16x32_bf16(k0, qf[s2][0], z, 0, 0, 0);
        sv[s2][c] = __builtin_amdgcn_mfma_f32_16x16x32_bf16(k1, qf[s2][1], z, 0, 0, 0);
      }
    }

    if (hn) {
      const u16* vap = reinterpret_cast<const u16*>(&va);
      const u16* vbp = reinterpret_cast<const u16*>(&vb2);
      int jv = kj * 2;
      int jb = jv >> 3, jlow = jv & 7;
#pragma unroll
      for (int i = 0; i < 8; ++i) {
        int d = kc * 8 + i;
        int key = (d ^ (d >> 3)) & 7;
        uint32_t pk = (uint32_t)vap[i] | ((uint32_t)vbp[i] << 16);
        *reinterpret_cast<uint32_t*>(&Vt[cur ^ 1][d * 64 + ((jb ^ key) << 3) + jlow]) = pk;
      }
    }

    bool tail = TG && (j0 + 64 > m);
    const u16* Vb = Vt[cur];
    bf16x8 vfr[2][4];

#pragma unroll
    for (int s2 = 0; s2 < NS; ++s2) {
      uint32_t pk[8];
#pragma unroll
      for (int c = 0; c < 4; ++c) {
        float p[4];
#pragma unroll
        for (int r = 0; r < 4; ++r) {
          float v = exp2f(sv[s2][c][r]);
          if (tail && (j0 + c * 16 + lg * 4 + r >= m)) v = 0.f;
          p[r] = v; ps[s2] += v;
        }
        pk[2 * c] = cvtpk(p[0], p[1]);
        pk[2 * c + 1] = cvtpk(p[2], p[3]);
      }
#pragma unroll
      for (int c = 0; c < 4; ++c) {
        int phys = (2 * c + (lg >> 1)) ^ psw;
        uint2 u; u.x = pk[2 * c]; u.y = pk[2 * c + 1];
        *reinterpret_cast<uint2*>(&Pl[w][s2][lr * 64 + (phys << 3) + ((lg & 1) << 2)]) = u;
      }
#pragma unroll
      for (int ks = 0; ks < 2; ++ks) {
        int physp = (ks * 4 + lg) ^ psw;
        bf16x8 pb = ld8s(&Pl[w][s2][lr * 64 + (physp << 3)]);
#pragma unroll
        for (int dt = 0; dt < 4; ++dt) {
          if (s2 == 0) {
            int d = dt * 16 + lr;
            int key = (d ^ (d >> 3)) & 7;
            vfr[ks][dt] = ld8s(&Vb[d * 64 + ((((ks << 2) + lg) ^ key) << 3)]);
          }
          o[s2][dt] = __builtin_amdgcn_mfma_f32_16x16x32_bf16(vfr[ks][dt], pb, o[s2][dt], 0, 0, 0);
        }
      }
    }
    __syncthreads();
    cur ^= 1;
  }

#pragma unroll
  for (int s2 = 0; s2 < NS; ++s2) {
    ps[s2] += __shfl_xor(ps[s2], 16, 64);
    ps[s2] += __shfl_xor(ps[s2], 32, 64);
    float inv = 1.f / ps[s2];
    int grow = (b << 11) + q0 + 64 * s2 + lr;
    u16* op = O + (size_t)grow * 1024 + h * 64 + lg * 4;
#pragma unroll
    for (int dt = 0; dt < 4; ++dt) {
      uint2 u;
      u.x = cvtpk(o[s2][dt][0] * inv, o[s2][dt][1] * inv);
      u.y = cvtpk(o[s2][dt][2] * inv, o[s2][dt][3] * inv);
      *reinterpret_cast<uint2*>(op + dt * 16) = u;
    }
  }
}

extern "C" void kernel_launch(void* const* d_in, const int* in_sizes, int n_in,
                              void* d_out, int out_size, void* d_ws, size_t ws_size,
                              hipStream_t stream) {
  const float* x_in = (const float*)d_in[0];
  const float* ctx_in = (const float*)d_in[1];
  const float* hint_in = (const float*)d_in[2];
  const float* ln1g = (const float*)d_in[3]; const float* ln1b = (const float*)d_in[4];
  const float* ln2g = (const float*)d_in[5]; const float* ln2b = (const float*)d_in[6];
  const float* ln3g = (const float*)d_in[7]; const float* ln3b = (const float*)d_in[8];
  const float* ln4g = (const float*)d_in[9]; const float* ln4b = (const float*)d_in[10];
  const float* a1wq = (const float*)d_in[11]; const float* a1wk = (const float*)d_in[12];
  const float* a1wv = (const float*)d_in[13]; const float* a1wo = (const float*)d_in[14];
  const float* a1bo = (const float*)d_in[15];
  const float* a2wq = (const float*)d_in[16]; const float* a2wk = (const float*)d_in[17];
  const float* a2wv = (const float*)d_in[18]; const float* a2wo = (const float*)d_in[19];
  const float* a2bo = (const float*)d_in[20];
  const float* a3wq = (const float*)d_in[21]; const float* a3wk = (const float*)d_in[22];
  const float* a3wv = (const float*)d_in[23]; const float* a3wo = (const float*)d_in[24];
  const float* a3bo = (const float*)d_in[25];
  const float* ffw1 = (const float*)d_in[26]; const float* ffb1 = (const float*)d_in[27];
  const float* ffw2 = (const float*)d_in[28]; const float* ffb2 = (const float*)d_in[29];

  char* wsb = (char*)d_ws;
  size_t off = 0;
  auto alloc = [&](size_t bytes) -> void* {
    void* p = wsb + off;
    off += (bytes + 255) & ~(size_t)255;
    return p;
  };
  u16* wqkv1t = (u16*)alloc(3072ull * 1024 * 2);
  u16* wo1t = (u16*)alloc(1024ull * 1024 * 2);
  u16* wq2t = (u16*)alloc(1024ull * 1024 * 2);
  u16* wkv2t = (u16*)alloc(2048ull * 1024 * 2);
  u16* wo2t = (u16*)alloc(1024ull * 1024 * 2);
  u16* wq3t = (u16*)alloc(1024ull * 1024 * 2);
  u16* wkv3t = (u16*)alloc(2048ull * 1024 * 2);
  u16* wo3t = (u16*)alloc(1024ull * 1024 * 2);
  u16* w1t = (u16*)alloc(8192ull * 1024 * 2);
  u16* w2t = (u16*)alloc(1024ull * 4096 * 2);
  float* b1p = (float*)alloc(8192ull * 4);
  u16* hintbf = (u16*)alloc(500ull * 1024 * 2);
  u16* ctxbf = (u16*)alloc(512ull * 1024 * 2);
  float* xbuf = (float*)alloc(4096ull * 1024 * 4);
  u16* hbf = (u16*)alloc(4096ull * 1024 * 2);
  u16* attnout = (u16*)alloc(4096ull * 1024 * 2);
  u16* qbuf = (u16*)alloc(4096ull * 1024 * 2);
  u16* kvbuf = (u16*)alloc(512ull * 2048 * 2);
  u16* qkv = (u16*)alloc(4096ull * 4096 * 2);  // union: qkv [4096][3072] / g [4096][4096]
  u16* gbuf = qkv;

  // ---- batched weight/activation prep: one launch ----
  PrepArgs pa;
  int bi = 0, bc = 0;
  auto addJ = [&](const void* s, void* d, int K, int N, int mode, int roff,
                  int ldo, int slo, int shi, int nblk) {
    pa.j[bi].src = s; pa.j[bi].dst = d; pa.j[bi].K = K; pa.j[bi].N = N;
    pa.j[bi].mode = mode; pa.j[bi].row_off = roff; pa.j[bi].ldo = ldo;
    pa.j[bi].s_lo = slo; pa.j[bi].s_hi = shi; pa.j[bi].blk0 = bc;
    bc += nblk; ++bi;
  };
  addJ(a1wq, wqkv1t, 1024, 1024, 0, 0, 1024, 0, 1024, 1024);     // scaled (Q)
  addJ(a1wk, wqkv1t, 1024, 1024, 0, 1024, 1024, 0, 0, 1024);
  addJ(a1wv, wqkv1t, 1024, 1024, 0, 2048, 1024, 0, 0, 1024);
  addJ(a1wo, wo1t, 1024, 1024, 0, 0, 1024, 0, 0, 1024);
  addJ(a2wq, wq2t, 1024, 1024, 0, 0, 1024, 0, 1024, 1024);       // scaled (Q)
  addJ(a2wk, wkv2t, 1024, 1024, 0, 0, 1024, 0, 0, 1024);
  addJ(a2wv, wkv2t, 1024, 1024, 0, 1024, 1024, 0, 0, 1024);
  addJ(a2wo, wo2t, 1024, 1024, 0, 0, 1024, 0, 0, 1024);
  addJ(a3wq, wq3t, 1024, 1024, 0, 0, 1024, 0, 1024, 1024);       // scaled (Q)
  addJ(a3wk, wkv3t, 1024, 1024, 0, 0, 1024, 0, 0, 1024);
  addJ(a3wv, wkv3t, 1024, 1024, 0, 1024, 1024, 0, 0, 1024);
  addJ(a3wo, wo3t, 1024, 1024, 0, 0, 1024, 0, 0, 1024);
  addJ(ffw1, w1t, 1024, 8192, 1, 0, 1024, 0, 0, 8192);
  addJ(ffw2, w2t, 4096, 1024, 0, 0, 4096, 0, 0, 4096);
  addJ(ctx_in, ctxbf, 0, 0, 2, 0, 0, 0, 0, 512);
  addJ(hint_in, hintbf, 0, 0, 3, 0, 0, 0, 0, 500);
  addJ(ffb1, b1p, 0, 0, 4, 0, 0, 0, 0, 32);
  wprep_kernel<<<bc, 256, 0, stream>>>(pa);

  // ---- stage 1: self-attention ----
  ln_kernel<<<4096, 256, 0, stream>>>(x_in, ln1g, ln1b, hbf);
  gemm256_kernel<0><<<dim3(12, 16), 512, 0, stream>>>(hbf, 1024, wqkv1t, qkv, 3072,
                                                      nullptr, 4096, 3072, 1024);
  attn_kernel<false, 2><<<dim3(16, 16, 2), 256, 0, stream>>>(
      qkv, 3072, 0, qkv, 3072, 1024, 2048, 2048, attnout);
  gemm64_kernel<1><<<dim3(16, 32), 256, 0, stream>>>(attnout, 1024, wo1t, xbuf, 1024,
                                                     a1bo, x_in, 4096, 1024, 1024);

  // ---- stage 2: cross-attention over context ----
  ln_kernel<<<4096, 256, 0, stream>>>(xbuf, ln2g, ln2b, hbf);
  gemm64_kernel<0><<<dim3(16, 32), 256, 0, stream>>>(hbf, 1024, wq2t, qbuf, 1024,
                                                     nullptr, nullptr, 4096, 1024, 1024);
  gemm_bt_kernel<0, false><<<dim3(16, 4), 256, 0, stream>>>(ctxbf, 1024, wkv2t, kvbuf, 2048,
                                                            nullptr, nullptr, 512, 2048, 1024);
  attn_kernel<false, 2><<<dim3(16, 16, 2), 256, 0, stream>>>(
      qbuf, 1024, 0, kvbuf, 2048, 0, 1024, 256, attnout);
  gemm64_kernel<1><<<dim3(16, 32), 256, 0, stream>>>(attnout, 1024, wo2t, xbuf, 1024,
                                                     a2bo, xbuf, 4096, 1024, 1024);

  // ---- stage 3: video cross-attention (uses ln4) ----
  ln_kernel<<<4096, 256, 0, stream>>>(xbuf, ln4g, ln4b, hbf);
  gemm64_kernel<0><<<dim3(16, 32), 256, 0, stream>>>(hbf, 1024, wq3t, qbuf, 1024,
                                                     nullptr, nullptr, 4096, 1024, 1024);
  gemm_bt_kernel<0, true><<<dim3(16, 4), 256, 0, stream>>>(hintbf, 1024, wkv3t, kvbuf, 2048,
                                                           nullptr, nullptr, 500, 2048, 1024);
  attn_kernel<true, 2><<<dim3(16, 16, 2), 256, 0, stream>>>(
      qbuf, 1024, 0, kvbuf, 2048, 0, 1024, 250, attnout);
  gemm64_kernel<1><<<dim3(16, 32), 256, 0, stream>>>(attnout, 1024, wo3t, xbuf, 1024,
                                                     a3bo, xbuf, 4096, 1024, 1024);

  // ---- GEGLU feed-forward (uses ln3) ----
  ln_kernel<<<4096, 256, 0, stream>>>(xbuf, ln3g, ln3b, hbf);
  gemm256_kernel<2><<<dim3(32, 16), 512, 0, stream>>>(hbf, 1024, w1t, gbuf, 4096,
                                                      b1p, 4096, 8192, 1024);
  gemm64_kernel<1><<<dim3(16, 32), 256, 0, stream>>>(gbuf, 4096, w2t, d_out, 1024,
                                                     ffb2, xbuf, 4096, 1024, 4096);
}

// Round 14
// 470.820 us; speedup vs baseline: 1.0421x; 1.0068x over previous
//
#include <hip/hip_runtime.h>
#include <cstdint>

typedef unsigned short u16;
typedef __bf16 bf16x8 __attribute__((ext_vector_type(8)));
typedef float f32x4 __attribute__((ext_vector_type(4)));

__device__ __forceinline__ u16 f2bf(float f) {
  union { float f; uint32_t u; } x; x.f = f;
  uint32_t r = x.u + 0x7FFFu + ((x.u >> 16) & 1u);
  return (u16)(r >> 16);
}
__device__ __forceinline__ bf16x8 ld8s(const u16* p) {
  return *reinterpret_cast<const bf16x8*>(p);
}
__device__ __forceinline__ float geluf(float x) {
  return 0.5f * x * (1.f + erff(x * 0.70710678118654752f));
}
__device__ __forceinline__ uint32_t cvtpk(float a, float b) {
  uint32_t r;
  asm("v_cvt_pk_bf16_f32 %0, %1, %2" : "=v"(r) : "v"(a), "v"(b));
  return r;
}
// async global->LDS, 16B per lane; lds dest must be wave-uniform base (+lane*16)
__device__ __forceinline__ void gload16(const u16* g, u16* l) {
  __builtin_amdgcn_global_load_lds(
      (__attribute__((address_space(1))) void*)const_cast<u16*>(g),
      (__attribute__((address_space(3))) void*)l, 16, 0, 0);
}

// ---------- batched weight prep: all transposes/converts in ONE launch ----------
struct PrepJob {
  const void* src; void* dst;
  int K, N, mode, row_off, ldo, s_lo, s_hi, blk0;
};
struct PrepArgs { PrepJob j[17]; };

__global__ __launch_bounds__(256) void wprep_kernel(PrepArgs a) {
  __shared__ float tile[32][33];
  int bid = blockIdx.x;
  int t = threadIdx.x;
  const float* src = nullptr; void* dst = nullptr;
  int K = 0, N = 0, mode = 0, roff = 0, ldo = 0, slo = 0, shi = 0, bl = 0;
#pragma unroll
  for (int i = 0; i < 17; ++i) {
    int lo = a.j[i].blk0;
    int hi = (i == 16) ? 0x7fffffff : a.j[i + 1].blk0;
    if (bid >= lo && bid < hi) {
      src = (const float*)a.j[i].src; dst = a.j[i].dst;
      K = a.j[i].K; N = a.j[i].N; mode = a.j[i].mode; roff = a.j[i].row_off;
      ldo = a.j[i].ldo; slo = a.j[i].s_lo; shi = a.j[i].s_hi; bl = bid - lo;
    }
  }
  (void)K;
  if (mode <= 1) {
    int nb = N >> 5;
    int bx = bl % nb, by = bl / nb;
    int tx = t & 31, ty = t >> 5;
    int n = bx * 32 + tx, kbase = by * 32;
#pragma unroll
    for (int r = 0; r < 4; ++r)
      tile[ty + r * 8][tx] = src[(size_t)(kbase + ty + r * 8) * N + n];
    __syncthreads();
#pragma unroll
    for (int r = 0; r < 4; ++r) {
      int nl = ty + r * 8, ng = bx * 32 + nl;
      int orow;
      if (mode == 0) orow = roff + ng;
      else {
        if (ng < 4096) orow = ((ng >> 4) << 5) + (ng & 15);
        else { int t2 = ng - 4096; orow = ((t2 >> 4) << 5) + 16 + (t2 & 15); }
      }
      float v = tile[tx][nl];
      if (mode == 0 && orow >= slo && orow < shi) v *= 0.18033688011112042f;  // 0.125*log2e
      ((u16*)dst)[(size_t)orow * ldo + kbase + tx] = f2bf(v);
    }
  } else if (mode == 2) {
    int idx = bl * 1024 + t * 4;
    float4 v = *reinterpret_cast<const float4*>(src + idx);
    ushort4 o;
    o.x = f2bf(v.x); o.y = f2bf(v.y); o.z = f2bf(v.z); o.w = f2bf(v.w);
    *reinterpret_cast<ushort4*>((u16*)dst + idx) = o;
  } else if (mode == 3) {
    int row = bl;
    int tt = row % 250;
    int d0 = t * 4;
    int i0 = d0 >> 1;
    float den0 = powf(10000.f, (float)i0 / 512.f);
    float den1 = powf(10000.f, (float)(i0 + 1) / 512.f);
    float a0 = (float)tt / den0, a1 = (float)tt / den1;
    const float* hp = src + (size_t)row * 1024 + d0;
    u16* op = (u16*)dst + (size_t)row * 1024 + d0;
    op[0] = f2bf(hp[0] + sinf(a0));
    op[1] = f2bf(hp[1] + cosf(a0));
    op[2] = f2bf(hp[2] + sinf(a1));
    op[3] = f2bf(hp[3] + cosf(a1));
  } else {
    int i2 = bl * 256 + t;
    int g = i2 >> 5, s2 = i2 & 31;
    int c2 = (s2 < 16) ? (g * 16 + s2) : (4096 + g * 16 + (s2 - 16));
    ((float*)dst)[i2] = src[c2];
  }
}

// ---------- LayerNorm: f32 [rows][1024] -> bf16 ----------
__global__ __launch_bounds__(256) void ln_kernel(const float* __restrict__ x,
                                                 const float* __restrict__ g,
                                                 const float* __restrict__ b,
                                                 u16* __restrict__ out) {
  int row = blockIdx.x;
  int tid = threadIdx.x;
  int l = tid & 63, w = tid >> 6;
  const float4 v = reinterpret_cast<const float4*>(x + (size_t)row * 1024)[tid];
  float s = v.x + v.y + v.z + v.w;
#pragma unroll
  for (int d = 1; d < 64; d <<= 1) s += __shfl_xor(s, d, 64);
  __shared__ float red[8];
  if (l == 0) red[w] = s;
  __syncthreads();
  float mean = (red[0] + red[1] + red[2] + red[3]) * (1.f / 1024.f);
  float dx = v.x - mean, dy = v.y - mean, dz = v.z - mean, dw = v.w - mean;
  float vs = dx * dx + dy * dy + dz * dz + dw * dw;
#pragma unroll
  for (int d = 1; d < 64; d <<= 1) vs += __shfl_xor(vs, d, 64);
  if (l == 0) red[4 + w] = vs;
  __syncthreads();
  float var = (red[4] + red[5] + red[6] + red[7]) * (1.f / 1024.f);
  float rstd = rsqrtf(var + 1e-5f);
  const float4 g4 = reinterpret_cast<const float4*>(g)[tid];
  const float4 b4 = reinterpret_cast<const float4*>(b)[tid];
  ushort4 o;
  o.x = f2bf(dx * rstd * g4.x + b4.x);
  o.y = f2bf(dy * rstd * g4.y + b4.y);
  o.z = f2bf(dz * rstd * g4.z + b4.z);
  o.w = f2bf(dw * rstd * g4.w + b4.w);
  reinterpret_cast<ushort4*>(out + (size_t)row * 1024)[tid] = o;
}

// ---------- 256x256 8-phase GEMM (proven: ff1 91us / qkv1) ----------
template <int EPI>
__global__ __launch_bounds__(512, 2) void gemm256_kernel(
    const u16* __restrict__ A, int lda, const u16* __restrict__ Bt,
    void* __restrict__ Cv, int ldc, const float* __restrict__ bias,
    int M, int N, int K) {
  __shared__ __align__(16) u16 As[2][256 * 64];
  __shared__ __align__(16) u16 Bs[2][256 * 64];
  int t = threadIdx.x;
  int l = t & 63, w = t >> 6;
  int wm = w >> 2, wn = w & 3;
  int lr = l & 15, lg = l >> 4;
  int gx = gridDim.x;
  int nwg = gx * gridDim.y;
  int orig = blockIdx.y * gx + blockIdx.x;
  int qq = nwg >> 3, rr = nwg & 7;
  int xcd = orig & 7, lin = orig >> 3;
  int wg = (xcd < rr ? xcd * (qq + 1) : rr * (qq + 1) + (xcd - rr) * qq) + lin;
  int bx = wg % gx, by = wg / gx;
  int row0 = by * 256, n0 = bx * 256;

  int lrow8 = l >> 3, lchunk = l & 7;
  int csrc = (lchunk ^ lrow8) * 8;
  int keyA = lr & 7;
  int c0 = ((lg ^ keyA) << 3);
  int c1 = (((4 + lg) ^ keyA) << 3);

  f32x4 acc[8][4];
#pragma unroll
  for (int i = 0; i < 8; ++i)
#pragma unroll
    for (int j = 0; j < 4; ++j) acc[i][j] = f32x4{0.f, 0.f, 0.f, 0.f};

  auto stA = [&](int buf, int k0, int q) {
    int rb = q * 64 + w * 8;
    gload16(&A[(size_t)(row0 + rb + lrow8) * lda + k0 + csrc], &As[buf][rb * 64]);
  };
  auto stB = [&](int buf, int k0, int q) {
    int rb = q * 64 + w * 8;
    gload16(&Bt[(size_t)(n0 + rb + lrow8) * K + k0 + csrc], &Bs[buf][rb * 64]);
  };

  int nk = K >> 6;
  stB(0, 0, 0); stB(0, 0, 1); stB(0, 0, 2); stB(0, 0, 3);
  stA(0, 0, 0); stA(0, 0, 2); stA(0, 0, 1); stA(0, 0, 3);
  asm volatile("s_waitcnt vmcnt(2)" ::: "memory");
  __builtin_amdgcn_sched_barrier(0);
  asm volatile("s_barrier" ::: "memory");

  for (int ti = 0; ti < nk; ++ti) {
    int cur = ti & 1, nxt = cur ^ 1;
    bool hn = (ti + 1 < nk);
    int k0n = (ti + 1) << 6;
    const u16* Ab = As[cur];
    const u16* Bb = Bs[cur];
    bf16x8 a[4], b[4];

#pragma unroll
    for (int mi = 0; mi < 4; ++mi) a[mi] = ld8s(&Ab[(wm * 128 + mi * 16 + lr) * 64 + c0]);
#pragma unroll
    for (int ni = 0; ni < 4; ++ni) b[ni] = ld8s(&Bb[(wn * 64 + ni * 16 + lr) * 64 + c0]);
    if (hn) { stB(nxt, k0n, 0); stB(nxt, k0n, 1); }
    asm volatile("s_barrier" ::: "memory");
    __builtin_amdgcn_s_setprio(1);
#pragma unroll
    for (int mi = 0; mi < 4; ++mi)
#pragma unroll
      for (int ni = 0; ni < 4; ++ni)
        acc[mi][ni] = __builtin_amdgcn_mfma_f32_16x16x32_bf16(a[mi], b[ni], acc[mi][ni], 0, 0, 0);
    __builtin_amdgcn_s_setprio(0);
    if (hn) asm volatile("s_waitcnt vmcnt(2)" ::: "memory");
    else    asm volatile("s_waitcnt vmcnt(0)" ::: "memory");
    __builtin_amdgcn_sched_barrier(0);
    asm volatile("s_barrier" ::: "memory");

#pragma unroll
    for (int mi = 0; mi < 4; ++mi) a[mi] = ld8s(&Ab[(wm * 128 + (mi + 4) * 16 + lr) * 64 + c0]);
    if (hn) { stB(nxt, k0n, 2); stB(nxt, k0n, 3); }
    asm volatile("s_barrier" ::: "memory");
    __builtin_amdgcn_s_setprio(1);
#pragma unroll
    for (int mi = 0; mi < 4; ++mi)
#pragma unroll
      for (int ni = 0; ni < 4; ++ni)
        acc[mi + 4][ni] = __builtin_amdgcn_mfma_f32_16x16x32_bf16(a[mi], b[ni], acc[mi + 4][ni], 0, 0, 0);
    __builtin_amdgcn_s_setprio(0);
    asm volatile("s_barrier" ::: "memory");

#pragma unroll
    for (int mi = 0; mi < 4; ++mi) a[mi] = ld8s(&Ab[(wm * 128 + mi * 16 + lr) * 64 + c1]);
#pragma unroll
    for (int ni = 0; ni < 4; ++ni) b[ni] = ld8s(&Bb[(wn * 64 + ni * 16 + lr) * 64 + c1]);
    if (hn) { stA(nxt, k0n, 0); stA(nxt, k0n, 2); }
    asm volatile("s_barrier" ::: "memory");
    __builtin_amdgcn_s_setprio(1);
#pragma unroll
    for (int mi = 0; mi < 4; ++mi)
#pragma unroll
      for (int ni = 0; ni < 4; ++ni)
        acc[mi][ni] = __builtin_amdgcn_mfma_f32_16x16x32_bf16(a[mi], b[ni], acc[mi][ni], 0, 0, 0);
    __builtin_amdgcn_s_setprio(0);
    asm volatile("s_barrier" ::: "memory");

#pragma unroll
    for (int mi = 0; mi < 4; ++mi) a[mi] = ld8s(&Ab[(wm * 128 + (mi + 4) * 16 + lr) * 64 + c1]);
    if (hn) { stA(nxt, k0n, 1); stA(nxt, k0n, 3); }
    asm volatile("s_barrier" ::: "memory");
    __builtin_amdgcn_s_setprio(1);
#pragma unroll
    for (int mi = 0; mi < 4; ++mi)
#pragma unroll
      for (int ni = 0; ni < 4; ++ni)
        acc[mi + 4][ni] = __builtin_amdgcn_mfma_f32_16x16x32_bf16(a[mi], b[ni], acc[mi + 4][ni], 0, 0, 0);
    __builtin_amdgcn_s_setprio(0);
    if (hn) asm volatile("s_waitcnt vmcnt(2)" ::: "memory");
    __builtin_amdgcn_sched_barrier(0);
    asm volatile("s_barrier" ::: "memory");
  }

#pragma unroll
  for (int mi = 0; mi < 8; ++mi) {
    int rowb = row0 + wm * 128 + mi * 16 + lg * 4;
    if (EPI == 2) {
#pragma unroll
      for (int p = 0; p < 2; ++p) {
        int colA = n0 + wn * 64 + p * 32 + lr;
        int colG = colA + 16;
        int ocol = ((n0 + wn * 64) >> 1) + p * 16 + lr;
#pragma unroll
        for (int r = 0; r < 4; ++r) {
          float av = acc[mi][2 * p][r] + bias[colA];
          float gv = acc[mi][2 * p + 1][r] + bias[colG];
          ((u16*)Cv)[(size_t)(rowb + r) * ldc + ocol] = f2bf(av * geluf(gv));
        }
      }
    } else {
#pragma unroll
      for (int ni = 0; ni < 4; ++ni) {
        int gcol = n0 + wn * 64 + ni * 16 + lr;
#pragma unroll
        for (int r = 0; r < 4; ++r)
          ((u16*)Cv)[(size_t)(rowb + r) * ldc + gcol] = f2bf(acc[mi][ni][r]);
      }
    }
  }
}

// ---------- GEMM 128x64 pipelined (counted vmcnt, dbuf, 3 blocks/CU) ----------
template <int EPI>
__global__ __launch_bounds__(256) void gemm64_kernel(
    const u16* __restrict__ A, int lda, const u16* __restrict__ Bt,
    void* __restrict__ Cv, int ldc, const float* __restrict__ bias,
    const float* __restrict__ res, int M, int N, int K) {
  __shared__ __align__(16) u16 As[2][128 * 64];
  __shared__ __align__(16) u16 Bs[2][64 * 64];
  int t = threadIdx.x;
  int l = t & 63, w = t >> 6;
  int wm = w >> 1, wn = w & 1;
  int lr = l & 15, lg = l >> 4;
  int gx = gridDim.x;
  int nwg = gx * gridDim.y;
  int orig = blockIdx.y * gx + blockIdx.x;
  int qq = nwg >> 3, rr = nwg & 7;
  int xcd = orig & 7, lin = orig >> 3;
  int wg = (xcd < rr ? xcd * (qq + 1) : rr * (qq + 1) + (xcd - rr) * qq) + lin;
  int bx = wg % gx, by = wg / gx;
  int row0 = by * 128, n0 = bx * 64;

  int lrow8 = l >> 3, lchunk = l & 7;
  int csrc = (lchunk ^ lrow8) * 8;
  int keyA = lr & 7;
  f32x4 acc[4][2];
#pragma unroll
  for (int i = 0; i < 4; ++i)
#pragma unroll
    for (int j = 0; j < 2; ++j) acc[i][j] = f32x4{0.f, 0.f, 0.f, 0.f};

  auto stage = [&](int buf, int k0) {
#pragma unroll
    for (int q = 0; q < 4; ++q) {
      int rb = q * 32 + w * 8;
      gload16(&A[(size_t)(row0 + rb + lrow8) * lda + k0 + csrc], &As[buf][rb * 64]);
    }
#pragma unroll
    for (int q = 0; q < 2; ++q) {
      int rb = q * 32 + w * 8;
      gload16(&Bt[(size_t)(n0 + rb + lrow8) * K + k0 + csrc], &Bs[buf][rb * 64]);
    }
  };

  int nk = K >> 6;
  stage(0, 0);
  if (nk > 1) {
    stage(1, 64);
    asm volatile("s_waitcnt vmcnt(6)" ::: "memory");
  } else {
    asm volatile("s_waitcnt vmcnt(0)" ::: "memory");
  }
  __builtin_amdgcn_sched_barrier(0);
  __builtin_amdgcn_s_barrier();
  int cur = 0;
  for (int ti = 0; ti < nk; ++ti) {
    __builtin_amdgcn_s_setprio(1);
#pragma unroll
    for (int kk = 0; kk < 2; ++kk) {
      bf16x8 af[4], bfv[2];
#pragma unroll
      for (int mi = 0; mi < 4; ++mi)
        af[mi] = ld8s(&As[cur][(wm * 64 + mi * 16 + lr) * 64 + ((((kk << 2) + lg) ^ keyA) << 3)]);
#pragma unroll
      for (int ni = 0; ni < 2; ++ni)
        bfv[ni] = ld8s(&Bs[cur][(wn * 32 + ni * 16 + lr) * 64 + ((((kk << 2) + lg) ^ keyA) << 3)]);
#pragma unroll
      for (int mi = 0; mi < 4; ++mi)
#pragma unroll
        for (int ni = 0; ni < 2; ++ni)
          acc[mi][ni] = __builtin_amdgcn_mfma_f32_16x16x32_bf16(af[mi], bfv[ni], acc[mi][ni], 0, 0, 0);
    }
    __builtin_amdgcn_s_setprio(0);
    __builtin_amdgcn_sched_barrier(0);
    __builtin_amdgcn_s_barrier();
    if (ti + 2 < nk) {
      stage(cur, (ti + 2) << 6);
      asm volatile("s_waitcnt vmcnt(6)" ::: "memory");
    } else {
      asm volatile("s_waitcnt vmcnt(0)" ::: "memory");
    }
    __builtin_amdgcn_sched_barrier(0);
    __builtin_amdgcn_s_barrier();
    cur ^= 1;
  }

#pragma unroll
  for (int mi = 0; mi < 4; ++mi) {
    int rowb = row0 + wm * 64 + mi * 16 + lg * 4;
#pragma unroll
    for (int ni = 0; ni < 2; ++ni) {
      int gcol = n0 + wn * 32 + ni * 16 + lr;
#pragma unroll
      for (int r = 0; r < 4; ++r) {
        int grow = rowb + r;
        float v = acc[mi][ni][r];
        if (EPI == 0)
          ((u16*)Cv)[(size_t)grow * ldc + gcol] = f2bf(v);
        else
          ((float*)Cv)[(size_t)grow * ldc + gcol] =
              v + bias[gcol] + res[(size_t)grow * ldc + gcol];
      }
    }
  }
}

// ---------- GEMM 128x128 pipelined (kv projections only) ----------
template <int EPI, bool GUARD>
__global__ __launch_bounds__(256) void gemm_bt_kernel(
    const u16* __restrict__ A, int lda, const u16* __restrict__ Bt,
    void* __restrict__ Cv, int ldc, const float* __restrict__ bias,
    const float* __restrict__ res, int M, int N, int K) {
  __shared__ __align__(16) u16 As[2][128 * 64];
  __shared__ __align__(16) u16 Bs[2][128 * 64];
  int t = threadIdx.x;
  int l = t & 63, w = t >> 6;
  int wm = w >> 1, wn = w & 1;
  int lr = l & 15, lg = l >> 4;
  int gx = gridDim.x;
  int nwg = gx * gridDim.y;
  int orig = blockIdx.y * gx + blockIdx.x;
  int qq = nwg >> 3, rr = nwg & 7;
  int xcd = orig & 7, lin = orig >> 3;
  int wg = (xcd < rr ? xcd * (qq + 1) : rr * (qq + 1) + (xcd - rr) * qq) + lin;
  int bx = wg % gx, by = wg / gx;
  int row0 = by * 128, n0 = bx * 128;

  int lrow8 = l >> 3, lchunk = l & 7;
  int csrc = (lchunk ^ lrow8) * 8;
  int keyA = lr & 7;
  f32x4 acc[4][4];
#pragma unroll
  for (int i = 0; i < 4; ++i)
#pragma unroll
    for (int j = 0; j < 4; ++j) acc[i][j] = f32x4{0.f, 0.f, 0.f, 0.f};

  auto stage = [&](int buf, int k0) {
#pragma unroll
    for (int q = 0; q < 4; ++q) {
      int rbase = w * 32 + q * 8;
      int r = rbase + lrow8;
      int ga = row0 + r;
      if (GUARD) { if (ga > M - 1) ga = M - 1; }
      gload16(&A[(size_t)ga * lda + k0 + csrc], &As[buf][rbase * 64]);
      gload16(&Bt[(size_t)(n0 + r) * K + k0 + csrc], &Bs[buf][rbase * 64]);
    }
  };

  int nk = K >> 6;
  stage(0, 0);
  if (nk > 1) {
    stage(1, 64);
    asm volatile("s_waitcnt vmcnt(8)" ::: "memory");
  } else {
    asm volatile("s_waitcnt vmcnt(0)" ::: "memory");
  }
  __builtin_amdgcn_sched_barrier(0);
  __builtin_amdgcn_s_barrier();
  int cur = 0;
  for (int ti = 0; ti < nk; ++ti) {
    __builtin_amdgcn_s_setprio(1);
#pragma unroll
    for (int kk = 0; kk < 2; ++kk) {
      bf16x8 af[4], bfv[4];
#pragma unroll
      for (int mi = 0; mi < 4; ++mi)
        af[mi] = ld8s(&As[cur][(wm * 64 + mi * 16 + lr) * 64 + ((((kk << 2) + lg) ^ keyA) << 3)]);
#pragma unroll
      for (int ni = 0; ni < 4; ++ni)
        bfv[ni] = ld8s(&Bs[cur][(wn * 64 + ni * 16 + lr) * 64 + ((((kk << 2) + lg) ^ keyA) << 3)]);
#pragma unroll
      for (int mi = 0; mi < 4; ++mi)
#pragma unroll
        for (int ni = 0; ni < 4; ++ni)
          acc[mi][ni] = __builtin_amdgcn_mfma_f32_16x16x32_bf16(af[mi], bfv[ni], acc[mi][ni], 0, 0, 0);
    }
    __builtin_amdgcn_s_setprio(0);
    __builtin_amdgcn_sched_barrier(0);
    __builtin_amdgcn_s_barrier();
    if (ti + 2 < nk) {
      stage(cur, (ti + 2) << 6);
      asm volatile("s_waitcnt vmcnt(8)" ::: "memory");
    } else {
      asm volatile("s_waitcnt vmcnt(0)" ::: "memory");
    }
    __builtin_amdgcn_sched_barrier(0);
    __builtin_amdgcn_s_barrier();
    cur ^= 1;
  }

#pragma unroll
  for (int mi = 0; mi < 4; ++mi) {
    int rowb = row0 + wm * 64 + mi * 16 + lg * 4;
#pragma unroll
    for (int ni = 0; ni < 4; ++ni) {
      int gcol = n0 + wn * 64 + ni * 16 + lr;
#pragma unroll
      for (int r = 0; r < 4; ++r) {
        int grow = rowb + r;
        if (GUARD && grow >= M) continue;
        float v = acc[mi][ni][r];
        if (EPI == 0)
          ((u16*)Cv)[(size_t)grow * ldc + gcol] = f2bf(v);
        else
          ((float*)Cv)[(size_t)grow * ldc + gcol] =
              v + bias[gcol] + res[(size_t)grow * ldc + gcol];
      }
    }
  }
}

// ---------- fused attention: swapped-operand QK^T/PV, no-max softmax ----------
// Tile-body reordered: (1) P pack+store for BOTH sets before any PV (set1's
// VALU hides set0's P-write->read LDS latency), (2) next-tile Vt write moved
// to tile end so va/vb2 global-load latency is covered by the whole tile.
template <bool TG, int NS>
__global__ __launch_bounds__(256) void attn_kernel(
    const u16* __restrict__ Q, int qs, int qoff,
    const u16* __restrict__ KV, int kvs, int koff, int voff,
    int m, u16* __restrict__ O) {
  int b = blockIdx.z, h = blockIdx.y;
  int t = threadIdx.x;
  int l = t & 63, w = t >> 6;
  int lr = l & 15, lg = l >> 4;
  int q0 = blockIdx.x * (64 * NS) + w * 16;
  __shared__ __align__(16) u16 Ks[2][64 * 64];
  __shared__ __align__(16) u16 Vt[2][64 * 64];
  __shared__ __align__(16) u16 Pl[4][NS][16 * 64];

  bf16x8 qf[NS][2];
#pragma unroll
  for (int s2 = 0; s2 < NS; ++s2) {
    const u16* qrow = Q + (size_t)((b << 11) + q0 + 64 * s2 + lr) * qs + qoff + h * 64;
    qf[s2][0] = ld8s(qrow + lg * 8);
    qf[s2][1] = ld8s(qrow + 32 + lg * 8);
  }

  f32x4 o[NS][4];
  float ps[NS];
#pragma unroll
  for (int s2 = 0; s2 < NS; ++s2) {
    ps[s2] = 0.f;
#pragma unroll
    for (int r = 0; r < 4; ++r) o[s2][r] = f32x4{0.f, 0.f, 0.f, 0.f};
  }

  const u16* kvb = KV + (size_t)b * m * kvs + h * 64;
  int kj = t >> 3, kc = t & 7;
  int srcsw = ((l & 7) ^ (l >> 3)) << 3;
  int psw = (lr & 7) ^ ((lr & 8) >> 1);

  {
#pragma unroll
    for (int q2 = 0; q2 < 2; ++q2) {
      int gr = w * 16 + q2 * 8 + (l >> 3);
      if (TG) { if (gr > m - 1) gr = m - 1; }
      gload16(kvb + (size_t)gr * kvs + koff + srcsw, &Ks[0][(w * 16 + q2 * 8) * 64]);
    }
    int jv = kj * 2;
    int gv0 = jv, gv1 = jv + 1;
    if (TG) { if (gv0 > m - 1) gv0 = m - 1; if (gv1 > m - 1) gv1 = m - 1; }
    uint4 va = *reinterpret_cast<const uint4*>(kvb + (size_t)gv0 * kvs + voff + kc * 8);
    uint4 vb2 = *reinterpret_cast<const uint4*>(kvb + (size_t)gv1 * kvs + voff + kc * 8);
    const u16* vap = reinterpret_cast<const u16*>(&va);
    const u16* vbp = reinterpret_cast<const u16*>(&vb2);
    int jb = jv >> 3, jlow = jv & 7;
#pragma unroll
    for (int i = 0; i < 8; ++i) {
      int d = kc * 8 + i;
      int key = (d ^ (d >> 3)) & 7;
      uint32_t pk = (uint32_t)vap[i] | ((uint32_t)vbp[i] << 16);
      *reinterpret_cast<uint32_t*>(&Vt[0][d * 64 + ((jb ^ key) << 3) + jlow]) = pk;
    }
  }
  __syncthreads();

  int nj = (m + 63) >> 6;
  int cur = 0;
  for (int jt = 0; jt < nj; ++jt) {
    int j0 = jt << 6;
    bool hn = (jt + 1 < nj);
    uint4 va, vb2;
    if (hn) {
      int j0n = j0 + 64;
#pragma unroll
      for (int q2 = 0; q2 < 2; ++q2) {
        int gr = j0n + w * 16 + q2 * 8 + (l >> 3);
        if (TG) { if (gr > m - 1) gr = m - 1; }
        gload16(kvb + (size_t)gr * kvs + koff + srcsw, &Ks[cur ^ 1][(w * 16 + q2 * 8) * 64]);
      }
      int jv = kj * 2;
      int gv0 = j0n + jv, gv1 = j0n + jv + 1;
      if (TG) { if (gv0 > m - 1) gv0 = m - 1; if (gv1 > m - 1) gv1 = m - 1; }
      va = *reinterpret_cast<const uint4*>(kvb + (size_t)gv0 * kvs + voff + kc * 8);
      vb2 = *reinterpret_cast<const uint4*>(kvb + (size_t)gv1 * kvs + voff + kc * 8);
    }

    // ---- QK^T (swapped) for all sets ----
    const u16* Kb = Ks[cur];
    f32x4 sv[NS][4];
#pragma unroll
    for (int c = 0; c < 4; ++c) {
      bf16x8 k0 = ld8s(&Kb[(c * 16 + lr) * 64 + ((lg ^ (lr & 7)) << 3)]);
      bf16x8 k1 = ld8s(&Kb[(c * 16 + lr) * 64 + (((4 + lg) ^ (lr & 7)) << 3)]);
#pragma unroll
      for (int s2 = 0; s2 < NS; ++s2) {
        f32x4 z = f32x4{0.f, 0.f, 0.f, 0.f};
        z = __builtin_amdgcn_mfma_f32_16x16x32_bf16(k0, qf[s2][0], z, 0, 0, 0);
        sv[s2][c] = __builtin_amdgcn_mfma_f32_16x16x32_bf16(k1, qf[s2][1], z, 0, 0, 0);
      }
    }

    bool tail = TG && (j0 + 64 > m);
    const u16* Vb = Vt[cur];

    // ---- softmax + P pack/store for ALL sets first ----
#pragma unroll
    for (int s2 = 0; s2 < NS; ++s2) {
      uint32_t pk[8];
#pragma unroll
      for (int c = 0; c < 4; ++c) {
        float p[4];
#pragma unroll
        for (int r = 0; r < 4; ++r) {
          float v = exp2f(sv[s2][c][r]);
          if (tail && (j0 + c * 16 + lg * 4 + r >= m)) v = 0.f;
          p[r] = v; ps[s2] += v;
        }
        pk[2 * c] = cvtpk(p[0], p[1]);
        pk[2 * c + 1] = cvtpk(p[2], p[3]);
      }
#pragma unroll
      for (int c = 0; c < 4; ++c) {
        int phys = (2 * c + (lg >> 1)) ^ psw;
        uint2 u; u.x = pk[2 * c]; u.y = pk[2 * c + 1];
        *reinterpret_cast<uint2*>(&Pl[w][s2][lr * 64 + (phys << 3) + ((lg & 1) << 2)]) = u;
      }
    }

    // ---- V-frag reads (cover last P-writes) ----
    bf16x8 vfr[2][4];
#pragma unroll
    for (int ks = 0; ks < 2; ++ks)
#pragma unroll
      for (int dt = 0; dt < 4; ++dt) {
        int d = dt * 16 + lr;
        int key = (d ^ (d >> 3)) & 7;
        vfr[ks][dt] = ld8s(&Vb[d * 64 + ((((ks << 2) + lg) ^ key) << 3)]);
      }

    // ---- PV per set ----
#pragma unroll
    for (int s2 = 0; s2 < NS; ++s2) {
#pragma unroll
      for (int ks = 0; ks < 2; ++ks) {
        int physp = (ks * 4 + lg) ^ psw;
        bf16x8 pb = ld8s(&Pl[w][s2][lr * 64 + (physp << 3)]);
#pragma unroll
        for (int dt = 0; dt < 4; ++dt)
          o[s2][dt] = __builtin_amdgcn_mfma_f32_16x16x32_bf16(vfr[ks][dt], pb, o[s2][dt], 0, 0, 0);
      }
    }

    // ---- write V transpose for next tile (va/vb2 had the whole tile to land) ----
    if (hn) {
      const u16* vap = reinterpret_cast<const u16*>(&va);
      const u16* vbp = reinterpret_cast<const u16*>(&vb2);
      int jv = kj * 2;
      int jb = jv >> 3, jlow = jv & 7;
#pragma unroll
      for (int i = 0; i < 8; ++i) {
        int d = kc * 8 + i;
        int key = (d ^ (d >> 3)) & 7;
        uint32_t pk = (uint32_t)vap[i] | ((uint32_t)vbp[i] << 16);
        *reinterpret_cast<uint32_t*>(&Vt[cur ^ 1][d * 64 + ((jb ^ key) << 3) + jlow]) = pk;
      }
    }
    __syncthreads();
    cur ^= 1;
  }

#pragma unroll
  for (int s2 = 0; s2 < NS; ++s2) {
    ps[s2] += __shfl_xor(ps[s2], 16, 64);
    ps[s2] += __shfl_xor(ps[s2], 32, 64);
    float inv = 1.f / ps[s2];
    int grow = (b << 11) + q0 + 64 * s2 + lr;
    u16* op = O + (size_t)grow * 1024 + h * 64 + lg * 4;
#pragma unroll
    for (int dt = 0; dt < 4; ++dt) {
      uint2 u;
      u.x = cvtpk(o[s2][dt][0] * inv, o[s2][dt][1] * inv);
      u.y = cvtpk(o[s2][dt][2] * inv, o[s2][dt][3] * inv);
      *reinterpret_cast<uint2*>(op + dt * 16) = u;
    }
  }
}

extern "C" void kernel_launch(void* const* d_in, const int* in_sizes, int n_in,
                              void* d_out, int out_size, void* d_ws, size_t ws_size,
                              hipStream_t stream) {
  const float* x_in = (const float*)d_in[0];
  const float* ctx_in = (const float*)d_in[1];
  const float* hint_in = (const float*)d_in[2];
  const float* ln1g = (const float*)d_in[3]; const float* ln1b = (const float*)d_in[4];
  const float* ln2g = (const float*)d_in[5]; const float* ln2b = (const float*)d_in[6];
  const float* ln3g = (const float*)d_in[7]; const float* ln3b = (const float*)d_in[8];
  const float* ln4g = (const float*)d_in[9]; const float* ln4b = (const float*)d_in[10];
  const float* a1wq = (const float*)d_in[11]; const float* a1wk = (const float*)d_in[12];
  const float* a1wv = (const float*)d_in[13]; const float* a1wo = (const float*)d_in[14];
  const float* a1bo = (const float*)d_in[15];
  const float* a2wq = (const float*)d_in[16]; const float* a2wk = (const float*)d_in[17];
  const float* a2wv = (const float*)d_in[18]; const float* a2wo = (const float*)d_in[19];
  const float* a2bo = (const float*)d_in[20];
  const float* a3wq = (const float*)d_in[21]; const float* a3wk = (const float*)d_in[22];
  const float* a3wv = (const float*)d_in[23]; const float* a3wo = (const float*)d_in[24];
  const float* a3bo = (const float*)d_in[25];
  const float* ffw1 = (const float*)d_in[26]; const float* ffb1 = (const float*)d_in[27];
  const float* ffw2 = (const float*)d_in[28]; const float* ffb2 = (const float*)d_in[29];

  char* wsb = (char*)d_ws;
  size_t off = 0;
  auto alloc = [&](size_t bytes) -> void* {
    void* p = wsb + off;
    off += (bytes + 255) & ~(size_t)255;
    return p;
  };
  u16* wqkv1t = (u16*)alloc(3072ull * 1024 * 2);
  u16* wo1t = (u16*)alloc(1024ull * 1024 * 2);
  u16* wq2t = (u16*)alloc(1024ull * 1024 * 2);
  u16* wkv2t = (u16*)alloc(2048ull * 1024 * 2);
  u16* wo2t = (u16*)alloc(1024ull * 1024 * 2);
  u16* wq3t = (u16*)alloc(1024ull * 1024 * 2);
  u16* wkv3t = (u16*)alloc(2048ull * 1024 * 2);
  u16* wo3t = (u16*)alloc(1024ull * 1024 * 2);
  u16* w1t = (u16*)alloc(8192ull * 1024 * 2);
  u16* w2t = (u16*)alloc(1024ull * 4096 * 2);
  float* b1p = (float*)alloc(8192ull * 4);
  u16* hintbf = (u16*)alloc(500ull * 1024 * 2);
  u16* ctxbf = (u16*)alloc(512ull * 1024 * 2);
  float* xbuf = (float*)alloc(4096ull * 1024 * 4);
  u16* hbf = (u16*)alloc(4096ull * 1024 * 2);
  u16* attnout = (u16*)alloc(4096ull * 1024 * 2);
  u16* qbuf = (u16*)alloc(4096ull * 1024 * 2);
  u16* kvbuf = (u16*)alloc(512ull * 2048 * 2);
  u16* qkv = (u16*)alloc(4096ull * 4096 * 2);  // union: qkv [4096][3072] / g [4096][4096]
  u16* gbuf = qkv;

  // ---- batched weight/activation prep: one launch ----
  PrepArgs pa;
  int bi = 0, bc = 0;
  auto addJ = [&](const void* s, void* d, int K, int N, int mode, int roff,
                  int ldo, int slo, int shi, int nblk) {
    pa.j[bi].src = s; pa.j[bi].dst = d; pa.j[bi].K = K; pa.j[bi].N = N;
    pa.j[bi].mode = mode; pa.j[bi].row_off = roff; pa.j[bi].ldo = ldo;
    pa.j[bi].s_lo = slo; pa.j[bi].s_hi = shi; pa.j[bi].blk0 = bc;
    bc += nblk; ++bi;
  };
  addJ(a1wq, wqkv1t, 1024, 1024, 0, 0, 1024, 0, 1024, 1024);     // scaled (Q)
  addJ(a1wk, wqkv1t, 1024, 1024, 0, 1024, 1024, 0, 0, 1024);
  addJ(a1wv, wqkv1t, 1024, 1024, 0, 2048, 1024, 0, 0, 1024);
  addJ(a1wo, wo1t, 1024, 1024, 0, 0, 1024, 0, 0, 1024);
  addJ(a2wq, wq2t, 1024, 1024, 0, 0, 1024, 0, 1024, 1024);       // scaled (Q)
  addJ(a2wk, wkv2t, 1024, 1024, 0, 0, 1024, 0, 0, 1024);
  addJ(a2wv, wkv2t, 1024, 1024, 0, 1024, 1024, 0, 0, 1024);
  addJ(a2wo, wo2t, 1024, 1024, 0, 0, 1024, 0, 0, 1024);
  addJ(a3wq, wq3t, 1024, 1024, 0, 0, 1024, 0, 1024, 1024);       // scaled (Q)
  addJ(a3wk, wkv3t, 1024, 1024, 0, 0, 1024, 0, 0, 1024);
  addJ(a3wv, wkv3t, 1024, 1024, 0, 1024, 1024, 0, 0, 1024);
  addJ(a3wo, wo3t, 1024, 1024, 0, 0, 1024, 0, 0, 1024);
  addJ(ffw1, w1t, 1024, 8192, 1, 0, 1024, 0, 0, 8192);
  addJ(ffw2, w2t, 4096, 1024, 0, 0, 4096, 0, 0, 4096);
  addJ(ctx_in, ctxbf, 0, 0, 2, 0, 0, 0, 0, 512);
  addJ(hint_in, hintbf, 0, 0, 3, 0, 0, 0, 0, 500);
  addJ(ffb1, b1p, 0, 0, 4, 0, 0, 0, 0, 32);
  wprep_kernel<<<bc, 256, 0, stream>>>(pa);

  // ---- stage 1: self-attention ----
  ln_kernel<<<4096, 256, 0, stream>>>(x_in, ln1g, ln1b, hbf);
  gemm256_kernel<0><<<dim3(12, 16), 512, 0, stream>>>(hbf, 1024, wqkv1t, qkv, 3072,
                                                      nullptr, 4096, 3072, 1024);
  attn_kernel<false, 2><<<dim3(16, 16, 2), 256, 0, stream>>>(
      qkv, 3072, 0, qkv, 3072, 1024, 2048, 2048, attnout);
  gemm64_kernel<1><<<dim3(16, 32), 256, 0, stream>>>(attnout, 1024, wo1t, xbuf, 1024,
                                                     a1bo, x_in, 4096, 1024, 1024);

  // ---- stage 2: cross-attention over context ----
  ln_kernel<<<4096, 256, 0, stream>>>(xbuf, ln2g, ln2b, hbf);
  gemm64_kernel<0><<<dim3(16, 32), 256, 0, stream>>>(hbf, 1024, wq2t, qbuf, 1024,
                                                     nullptr, nullptr, 4096, 1024, 1024);
  gemm_bt_kernel<0, false><<<dim3(16, 4), 256, 0, stream>>>(ctxbf, 1024, wkv2t, kvbuf, 2048,
                                                            nullptr, nullptr, 512, 2048, 1024);
  attn_kernel<false, 2><<<dim3(16, 16, 2), 256, 0, stream>>>(
      qbuf, 1024, 0, kvbuf, 2048, 0, 1024, 256, attnout);
  gemm64_kernel<1><<<dim3(16, 32), 256, 0, stream>>>(attnout, 1024, wo2t, xbuf, 1024,
                                                     a2bo, xbuf, 4096, 1024, 1024);

  // ---- stage 3: video cross-attention (uses ln4) ----
  ln_kernel<<<4096, 256, 0, stream>>>(xbuf, ln4g, ln4b, hbf);
  gemm64_kernel<0><<<dim3(16, 32), 256, 0, stream>>>(hbf, 1024, wq3t, qbuf, 1024,
                                                     nullptr, nullptr, 4096, 1024, 1024);
  gemm_bt_kernel<0, true><<<dim3(16, 4), 256, 0, stream>>>(hintbf, 1024, wkv3t, kvbuf, 2048,
                                                           nullptr, nullptr, 500, 2048, 1024);
  attn_kernel<true, 2><<<dim3(16, 16, 2), 256, 0, stream>>>(
      qbuf, 1024, 0, kvbuf, 2048, 0, 1024, 250, attnout);
  gemm64_kernel<1><<<dim3(16, 32), 256, 0, stream>>>(attnout, 1024, wo3t, xbuf, 1024,
                                                     a3bo, xbuf, 4096, 1024, 1024);

  // ---- GEGLU feed-forward (uses ln3) ----
  ln_kernel<<<4096, 256, 0, stream>>>(xbuf, ln3g, ln3b, hbf);
  gemm256_kernel<2><<<dim3(32, 16), 512, 0, stream>>>(hbf, 1024, w1t, gbuf, 4096,
                                                      b1p, 4096, 8192, 1024);
  gemm64_kernel<1><<<dim3(16, 32), 256, 0, stream>>>(gbuf, 4096, w2t, d_out, 1024,
                                                     ffb2, xbuf, 4096, 1024, 4096);
}